// Round 8
// baseline (490.887 us; speedup 1.0000x reference)
//
#include <hip/hip_runtime.h>
#include <math.h>

#define N_NODES 50000
#define N_EDGES 800000
#define N_B     64

typedef __attribute__((ext_vector_type(8))) short v8s;
typedef __attribute__((ext_vector_type(4))) float v4f;
typedef __attribute__((ext_vector_type(2))) float v2f;

__device__ __forceinline__ float lrelu(float x){ return x > 0.f ? x : 0.2f*x; }
__device__ __forceinline__ unsigned short f2b(float f){   // fp32 -> bf16 RNE
  unsigned u = __float_as_uint(f);
  return (unsigned short)((u + 0x7fffu + ((u >> 16) & 1u)) >> 16);
}
__device__ __forceinline__ float blo(unsigned u){ return __uint_as_float(u << 16); }
__device__ __forceinline__ float bhi(unsigned u){ return __uint_as_float(u & 0xffff0000u); }

// ---------------- conversion: weights -> transposed bf16 (+fused attn cols) ----------------
__global__ void k_conv(const float* __restrict__ Win, const float* __restrict__ Wl,
                       const float* __restrict__ a_src, const float* __restrict__ a_dst,
                       const float* __restrict__ Wg1,
                       unsigned short* __restrict__ WinT, unsigned short* __restrict__ WlT,
                       unsigned short* __restrict__ Wg1T){
  int i = blockIdx.x*256 + threadIdx.x;
  if (i < 16384){
    int n = i >> 7, k = i & 127;
    WinT[n*128+k] = f2b(Win[k*128+n]);
    return;
  }
  i -= 16384;
  if (i < 65536){
    int l = i >> 14, n = (i >> 7) & 127, k = i & 127;
    WlT[l*144*128 + n*128 + k] = f2b(Wl[l*16384 + k*128 + n]);
    return;
  }
  i -= 65536;
  if (i < 4096){
    int l = i >> 10, k = (i >> 3) & 127, t = i & 7;
    int hh = t & 3, sd = t >> 2;
    const float* av = (sd ? a_dst : a_src) + l*128 + hh*32;
    const float* wr = Wl + l*16384 + k*128 + hh*32;
    float s = 0.f;
    #pragma unroll
    for (int c = 0; c < 32; c++) s = fmaf(wr[c], av[c], s);
    WlT[l*144*128 + (128 + sd*4 + hh)*128 + k] = f2b(s);
    return;
  }
  i -= 4096;
  if (i < 4096){
    int l = i >> 10, r = (i >> 7) & 7, k = i & 127;
    WlT[l*144*128 + (136+r)*128 + k] = 0;
    return;
  }
  i -= 4096;
  if (i < 8192){
    int n = i >> 7, k = i & 127;
    Wg1T[n*128+k] = f2b(Wg1[k*64+n]);
  }
}

// ---------------- setup: zero cnt + graph boundaries (batch sorted) ----------------
__global__ void k_setup(const int* __restrict__ batch, int* __restrict__ start,
                        int* __restrict__ cnt){
  int i = blockIdx.x*256 + threadIdx.x;
  if (i >= N_NODES) return;
  cnt[i] = 0;
  int b = batch[i];
  int bp = (i == 0) ? -1 : batch[i-1];
  for (int j = bp+1; j <= b; j++) start[j] = i;
  if (i == N_NODES-1){
    for (int j = b+1; j <= N_B; j++) start[j] = N_NODES;
  }
}

// ---------------- degree histogram + per-edge rank (atomic returns old count) ----------------
__global__ void k_hist(const int* __restrict__ ei, int* __restrict__ cnt, int* __restrict__ rank){
  int t = blockIdx.x*256 + threadIdx.x;
  if (t >= 200000) return;
  #pragma unroll
  for (int r = 0; r < 4; r++){
    int e = t + r*200000;
    int d = ei[N_EDGES + e];
    rank[e] = atomicAdd(&cnt[d], 1);
  }
}

// ---------------- scan1: per-block inclusive scan ----------------
__global__ void k_scan1(const int* __restrict__ cnt, int* __restrict__ incl, int* __restrict__ part){
  __shared__ int sh[256];
  int tid = threadIdx.x, i = blockIdx.x*256 + tid;
  int v = (i < N_NODES) ? cnt[i] : 0;
  sh[tid] = v; __syncthreads();
  for (int off = 1; off < 256; off <<= 1){
    int t = (tid >= off) ? sh[tid-off] : 0;
    __syncthreads();
    sh[tid] += t; __syncthreads();
  }
  if (i < N_NODES) incl[i] = sh[tid];
  if (tid == 255) part[blockIdx.x] = sh[255];
}
// ---------------- scan23: each block reduces part[0..blockIdx) then writes off ----------------
__global__ void k_scan23(const int* __restrict__ cnt, const int* __restrict__ incl,
                         const int* __restrict__ part, int* __restrict__ off){
  __shared__ int red[4];
  __shared__ int bsum;
  int tid = threadIdx.x, lane = tid & 63, wave = tid >> 6;
  int v = (tid < (int)blockIdx.x) ? part[tid] : 0;   // 196 blocks < 256 threads
  #pragma unroll
  for (int m = 1; m < 64; m <<= 1) v += __shfl_xor(v, m);
  if (lane == 0) red[wave] = v;
  __syncthreads();
  if (tid == 0) bsum = red[0]+red[1]+red[2]+red[3];
  __syncthreads();
  int i = blockIdx.x*256 + tid;
  if (i >= N_NODES) return;
  int e = incl[i] - cnt[i] + bsum;
  off[i] = e;
  if (i == N_NODES-1) off[N_NODES] = e + cnt[i];
}

// ---------------- CSR fill + edge MLP scalar (atomic-free, single 8B scatter) ----------------
__global__ void k_fill(const float* __restrict__ ea, const float* __restrict__ We1,
                       const float* __restrict__ be1, const float* __restrict__ We2,
                       const float* __restrict__ be2, const int* __restrict__ ei,
                       const int* __restrict__ off, const int* __restrict__ rank,
                       int2* __restrict__ es){
  __shared__ float w0[16], w1[16], bb[16], w2s[16];
  __shared__ float b2s;
  int tid = threadIdx.x;
  if (tid < 16){
    w0[tid] = We1[tid]; w1[tid] = We1[16+tid]; bb[tid] = be1[tid];
    w2s[tid] = 0.25f*(We2[tid*4]+We2[tid*4+1]+We2[tid*4+2]+We2[tid*4+3]);
  }
  if (tid == 0) b2s = 0.25f*(be2[0]+be2[1]+be2[2]+be2[3]);
  __syncthreads();
  int t = blockIdx.x*256 + tid;
  if (t >= 200000) return;
  #pragma unroll
  for (int r = 0; r < 4; r++){
    int e = t + r*200000;
    float a0 = ea[2*e], a1 = ea[2*e+1];
    float s = b2s;
    #pragma unroll
    for (int j = 0; j < 16; j++){
      float v = fmaf(a0, w0[j], fmaf(a1, w1[j], bb[j]));
      v = v > 0.f ? v : 0.f;
      s = fmaf(v, w2s[j], s);
    }
    int d = ei[N_EDGES + e];
    int p = off[d] + rank[e];
    es[p] = make_int2(ei[e], __float_as_int(s));
  }
}

// ---------------- MFMA GEMM (AF32: A is fp32, converted during staging) ----------------
template<int NT, int MODE, bool AF32>
__global__ __launch_bounds__(256) void k_mgemm(
    const void* __restrict__ A, const unsigned short* __restrict__ Bt,
    const float* __restrict__ bias,
    float* __restrict__ h, unsigned short* __restrict__ hb,
    unsigned short* __restrict__ xpb, float* __restrict__ asn, float* __restrict__ adn,
    const float* __restrict__ Wg2, const float* __restrict__ bg2, float* __restrict__ gate)
{
  __shared__ __attribute__((aligned(16))) unsigned short Bs[NT*16][136];
  __shared__ __attribute__((aligned(16))) unsigned short As[4][16][136];
  int tid = threadIdx.x, wave = tid >> 6, lane = tid & 63;
  int l15 = lane & 15, quad = lane >> 4;
  int rbase = blockIdx.x * 64;
  for (int id = tid; id < NT*16*16; id += 256){
    int r = id >> 4, ch = id & 15;
    *(v8s*)&Bs[r][ch*8] = *(const v8s*)(Bt + r*128 + ch*8);
  }
  for (int id = tid; id < 64*16; id += 256){
    int r = id >> 4, ch = id & 15;
    int gr = rbase + r;
    v8s v = {0,0,0,0,0,0,0,0};
    if (gr < N_NODES){
      if (AF32){
        const float* Af = (const float*)A + (size_t)gr*128 + ch*8;
        float4 va = *(const float4*)Af;
        float4 vb = *(const float4*)(Af + 4);
        v[0]=(short)f2b(va.x); v[1]=(short)f2b(va.y); v[2]=(short)f2b(va.z); v[3]=(short)f2b(va.w);
        v[4]=(short)f2b(vb.x); v[5]=(short)f2b(vb.y); v[6]=(short)f2b(vb.z); v[7]=(short)f2b(vb.w);
      } else {
        v = *(const v8s*)((const unsigned short*)A + (size_t)gr*128 + ch*8);
      }
    }
    *(v8s*)&As[r >> 4][r & 15][ch*8] = v;
  }
  __syncthreads();
  v4f acc[NT];
  #pragma unroll
  for (int t = 0; t < NT; t++) acc[t] = (v4f){0.f,0.f,0.f,0.f};
  #pragma unroll
  for (int kb = 0; kb < 4; kb++){
    v8s a = *(v8s*)&As[wave][l15][kb*32 + quad*8];
    #pragma unroll
    for (int ct = 0; ct < NT; ct++){
      v8s b = *(v8s*)&Bs[ct*16 + l15][kb*32 + quad*8];
      acc[ct] = __builtin_amdgcn_mfma_f32_16x16x32_bf16(a, b, acc[ct], 0, 0, 0);
    }
  }
  int row0 = rbase + wave*16 + quad*4;
  if (MODE == 0){
    #pragma unroll
    for (int ct = 0; ct < 8; ct++){
      float bcol = bias[ct*16 + l15];
      #pragma unroll
      for (int r = 0; r < 4; r++){
        int gr = row0 + r;
        if (gr < N_NODES){
          float v = acc[ct][r] + bcol;
          h[(size_t)gr*128 + ct*16 + l15] = v;
          hb[(size_t)gr*128 + ct*16 + l15] = f2b(v);
        }
      }
    }
  } else if (MODE == 1){
    #pragma unroll
    for (int ct = 0; ct < 8; ct++){
      #pragma unroll
      for (int r = 0; r < 4; r++){
        int gr = row0 + r;
        if (gr < N_NODES) xpb[(size_t)gr*128 + ct*16 + l15] = f2b(acc[ct][r]);
      }
    }
    #pragma unroll
    for (int r = 0; r < 4; r++){
      int gr = row0 + r;
      if (gr < N_NODES){
        float v = acc[NT-1][r];
        if (l15 < 4) asn[gr*4 + l15] = v;
        else if (l15 < 8) adn[gr*4 + (l15-4)] = v;
      }
    }
  } else {
    float part[4] = {0.f,0.f,0.f,0.f};
    #pragma unroll
    for (int ct = 0; ct < NT; ct++){
      float b1 = bias[ct*16 + l15];
      float w2 = Wg2[ct*16 + l15];
      #pragma unroll
      for (int r = 0; r < 4; r++) part[r] = fmaf(tanhf(acc[ct][r] + b1), w2, part[r]);
    }
    #pragma unroll
    for (int m = 1; m < 16; m <<= 1){
      #pragma unroll
      for (int r = 0; r < 4; r++) part[r] += __shfl_xor(part[r], m);
    }
    if (l15 == 0){
      float b2 = bg2[0];
      #pragma unroll
      for (int r = 0; r < 4; r++){
        int gr = row0 + r;
        if (gr < N_NODES) gate[gr] = part[r] + b2;
      }
    }
  }
}

// ---------------- general (deg>64) single-node path ----------------
template<bool CRIT>
__device__ void aggr_node_general(int n, int base, int deg, int lane, float* myp,
    const unsigned* xw, const float* __restrict__ asn, const float* __restrict__ adn,
    const int2* __restrict__ es, const float* __restrict__ bl,
    const float* __restrict__ lng, const float* __restrict__ lnb,
    float* __restrict__ crit, float* __restrict__ h, unsigned short* __restrict__ hb)
{
  float4 ad4 = *(const float4*)(adn + n*4);
  float4 asf = *(const float4*)(asn + n*4);
  float ex = lrelu(asf.x+ad4.x), ey = lrelu(asf.y+ad4.y);
  float ez = lrelu(asf.z+ad4.z), ew = lrelu(asf.w+ad4.w);
  int hh = lane >> 4;
  float mx = ex, my = ey, mz = ez, mw = ew;
  float cw = 0.f;
  for (int j = lane; j < deg; j += 64){
    int2 er = es[base + j];
    float4 a = *(const float4*)(asn + er.x*4);
    mx = fmaxf(mx, lrelu(a.x+ad4.x)); my = fmaxf(my, lrelu(a.y+ad4.y));
    mz = fmaxf(mz, lrelu(a.z+ad4.z)); mw = fmaxf(mw, lrelu(a.w+ad4.w));
    if (CRIT) cw += __int_as_float(er.y);
  }
  #pragma unroll
  for (int m = 1; m < 64; m <<= 1){
    mx = fmaxf(mx, __shfl_xor(mx, m)); my = fmaxf(my, __shfl_xor(my, m));
    mz = fmaxf(mz, __shfl_xor(mz, m)); mw = fmaxf(mw, __shfl_xor(mw, m));
    if (CRIT) cw += __shfl_xor(cw, m);
  }
  float cr;
  if (CRIT){ if (lane == 0) crit[n] = cw; cr = cw; }
  else cr = crit[n];
  float psx = __expf(ex-mx), psy = __expf(ey-my), psz = __expf(ez-mz), psw = __expf(ew-mw);
  float pself = hh < 2 ? (hh == 0 ? psx : psy) : (hh == 2 ? psz : psw);
  unsigned us = (xw + ((size_t)(unsigned)n << 6))[lane];
  float acc0 = pself * blo(us), acc1 = pself * bhi(us);
  float sx = 0.f, sy = 0.f, sz = 0.f, sw = 0.f;
  for (int j0 = 0; j0 < deg; j0 += 64){
    int clen = deg - j0; if (clen > 64) clen = 64;
    int sreg = 0;
    float p0 = 0.f, p1 = 0.f, p2 = 0.f, p3 = 0.f;
    if (lane < clen){
      sreg = es[base + j0 + lane].x;
      float4 a = *(const float4*)(asn + sreg*4);
      p0 = __expf(lrelu(a.x+ad4.x)-mx);
      p1 = __expf(lrelu(a.y+ad4.y)-my);
      p2 = __expf(lrelu(a.z+ad4.z)-mz);
      p3 = __expf(lrelu(a.w+ad4.w)-mw);
      sx += p0; sy += p1; sz += p2; sw += p3;
    }
    *(float4*)(&myp[4*lane]) = make_float4(p0,p1,p2,p3);
    __threadfence_block();
    int clenR = (clen + 7) & ~7;
    for (int c = 0; c < clenR; c += 8){
      unsigned u[8];
      #pragma unroll
      for (int k = 0; k < 8; k++){
        int s0 = __builtin_amdgcn_readlane(sreg, c + k);
        u[k] = (xw + ((size_t)(unsigned)s0 << 6))[lane];
      }
      #pragma unroll
      for (int k = 0; k < 8; k++){
        float q = myp[4*(c+k) + hh];
        acc0 = fmaf(q, blo(u[k]), acc0);
        acc1 = fmaf(q, bhi(u[k]), acc1);
      }
    }
    __threadfence_block();
  }
  #pragma unroll
  for (int m = 1; m < 64; m <<= 1){
    sx += __shfl_xor(sx, m); sy += __shfl_xor(sy, m);
    sz += __shfl_xor(sz, m); sw += __shfl_xor(sw, m);
  }
  sx += psx; sy += psy; sz += psz; sw += psw;
  float den = (hh < 2 ? (hh == 0 ? sx : sy) : (hh == 2 ? sz : sw)) + 1e-16f;
  float rden = 1.f / den;
  int c0 = 2*lane;
  float2 blv = *(const float2*)(bl + c0);
  float o0 = acc0*rden + blv.x;
  float o1 = acc1*rden + blv.y;
  float su = o0 + o1, sq = o0*o0 + o1*o1;
  #pragma unroll
  for (int m = 1; m < 64; m <<= 1){ su += __shfl_xor(su, m); sq += __shfl_xor(sq, m); }
  float mu  = su * (1.f/128.f);
  float var = sq * (1.f/128.f) - mu*mu; var = var > 0.f ? var : 0.f;
  float inv = rsqrtf(var + 1e-5f);
  float2 rv  = *(const float2*)(h + (size_t)n*128 + c0);
  float2 gv  = *(const float2*)(lng + c0);
  float2 bv2 = *(const float2*)(lnb + c0);
  o0 = (o0-mu)*inv*gv.x + bv2.x + cr + rv.x;
  o1 = (o1-mu)*inv*gv.y + bv2.y + cr + rv.y;
  *(float2*)(&h[(size_t)n*128 + c0]) = make_float2(o0, o1);
  *(unsigned*)(&hb[(size_t)n*128 + c0]) = ((unsigned)f2b(o1) << 16) | f2b(o0);
}

// ---------------- per-node GAT aggregate, v7: 2 nodes per wave, interleaved ----------------
// grid*8 == N_NODES exactly (6250*8=50000) -> no bounds checks.
template<bool CRIT>
__global__ __launch_bounds__(256) void k_aggr(
    const unsigned short* __restrict__ xpb, const float* __restrict__ asn,
    const float* __restrict__ adn, const int* __restrict__ off,
    const int2* __restrict__ es,
    const float* __restrict__ bl, const float* __restrict__ lng,
    const float* __restrict__ lnb, float* __restrict__ crit,
    float* __restrict__ h, unsigned short* __restrict__ hb)
{
  __shared__ float lp[4][2][256];
  int wave = threadIdx.x >> 6, lane = threadIdx.x & 63;
  int n0 = blockIdx.x*8 + wave*2;
  int n1 = n0 + 1;
  int b0 = off[n0], b1 = off[n1], b2 = off[n1+1];
  int deg0 = b1 - b0, deg1 = b2 - b1;
  const unsigned* xw = (const unsigned*)xpb;
  if (deg0 > 64 || deg1 > 64){
    aggr_node_general<CRIT>(n0, b0, deg0, lane, &lp[wave][0][0], xw, asn, adn, es,
                            bl, lng, lnb, crit, h, hb);
    aggr_node_general<CRIT>(n1, b1, deg1, lane, &lp[wave][1][0], xw, asn, adn, es,
                            bl, lng, lnb, crit, h, hb);
    return;
  }
  float4 ad0 = *(const float4*)(adn + n0*4);
  float4 as0 = *(const float4*)(asn + n0*4);
  float4 ad1 = *(const float4*)(adn + n1*4);
  float4 as1 = *(const float4*)(asn + n1*4);
  float ex0 = lrelu(as0.x+ad0.x), ey0 = lrelu(as0.y+ad0.y);
  float ez0 = lrelu(as0.z+ad0.z), ew0 = lrelu(as0.w+ad0.w);
  float ex1 = lrelu(as1.x+ad1.x), ey1 = lrelu(as1.y+ad1.y);
  float ez1 = lrelu(as1.z+ad1.z), ew1 = lrelu(as1.w+ad1.w);
  int sreg0 = 0, sreg1 = 0;
  float c0w = 0.f, c1w = 0.f;
  float e00=-3.0e38f, e01=-3.0e38f, e02=-3.0e38f, e03=-3.0e38f;
  float e10=-3.0e38f, e11=-3.0e38f, e12=-3.0e38f, e13=-3.0e38f;
  if (lane < deg0){
    int2 er = es[b0 + lane];
    sreg0 = er.x;
    float4 a = *(const float4*)(asn + sreg0*4);
    e00 = lrelu(a.x+ad0.x); e01 = lrelu(a.y+ad0.y);
    e02 = lrelu(a.z+ad0.z); e03 = lrelu(a.w+ad0.w);
    if (CRIT) c0w = __int_as_float(er.y);
  }
  if (lane < deg1){
    int2 er = es[b1 + lane];
    sreg1 = er.x;
    float4 a = *(const float4*)(asn + sreg1*4);
    e10 = lrelu(a.x+ad1.x); e11 = lrelu(a.y+ad1.y);
    e12 = lrelu(a.z+ad1.z); e13 = lrelu(a.w+ad1.w);
    if (CRIT) c1w = __int_as_float(er.y);
  }
  float mx0 = fmaxf(e00,ex0), my0 = fmaxf(e01,ey0), mz0 = fmaxf(e02,ez0), mw0 = fmaxf(e03,ew0);
  float mx1 = fmaxf(e10,ex1), my1 = fmaxf(e11,ey1), mz1 = fmaxf(e12,ez1), mw1 = fmaxf(e13,ew1);
  #pragma unroll
  for (int m = 1; m < 64; m <<= 1){
    mx0 = fmaxf(mx0, __shfl_xor(mx0, m)); my0 = fmaxf(my0, __shfl_xor(my0, m));
    mz0 = fmaxf(mz0, __shfl_xor(mz0, m)); mw0 = fmaxf(mw0, __shfl_xor(mw0, m));
    mx1 = fmaxf(mx1, __shfl_xor(mx1, m)); my1 = fmaxf(my1, __shfl_xor(my1, m));
    mz1 = fmaxf(mz1, __shfl_xor(mz1, m)); mw1 = fmaxf(mw1, __shfl_xor(mw1, m));
    if (CRIT){ c0w += __shfl_xor(c0w, m); c1w += __shfl_xor(c1w, m); }
  }
  float cr0, cr1;
  if (CRIT){
    if (lane == 0){ crit[n0] = c0w; crit[n1] = c1w; }
    cr0 = c0w; cr1 = c1w;
  } else { cr0 = crit[n0]; cr1 = crit[n1]; }
  float ps0x = __expf(ex0-mx0), ps0y = __expf(ey0-my0), ps0z = __expf(ez0-mz0), ps0w = __expf(ew0-mw0);
  float ps1x = __expf(ex1-mx1), ps1y = __expf(ey1-my1), ps1z = __expf(ez1-mz1), ps1w = __expf(ew1-mw1);
  float p00=0.f,p01=0.f,p02=0.f,p03=0.f, p10=0.f,p11=0.f,p12=0.f,p13=0.f;
  if (lane < deg0){
    p00 = __expf(e00-mx0); p01 = __expf(e01-my0); p02 = __expf(e02-mz0); p03 = __expf(e03-mw0);
  }
  if (lane < deg1){
    p10 = __expf(e10-mx1); p11 = __expf(e11-my1); p12 = __expf(e12-mz1); p13 = __expf(e13-mw1);
  }
  float s0x=p00, s0y=p01, s0z=p02, s0w=p03;
  float s1x=p10, s1y=p11, s1z=p12, s1w=p13;
  float* myp0 = &lp[wave][0][0];
  float* myp1 = &lp[wave][1][0];
  *(float4*)(&myp0[4*lane]) = make_float4(p00,p01,p02,p03);
  *(float4*)(&myp1[4*lane]) = make_float4(p10,p11,p12,p13);
  __threadfence_block();
  int hh = lane >> 4;
  float pself0 = hh < 2 ? (hh == 0 ? ps0x : ps0y) : (hh == 2 ? ps0z : ps0w);
  float pself1 = hh < 2 ? (hh == 0 ? ps1x : ps1y) : (hh == 2 ? ps1z : ps1w);
  unsigned us0 = (xw + ((size_t)(unsigned)n0 << 6))[lane];
  unsigned us1 = (xw + ((size_t)(unsigned)n1 << 6))[lane];
  v2f acc0 = {pself0*blo(us0), pself0*bhi(us0)};
  v2f acc1 = {pself1*blo(us1), pself1*bhi(us1)};
  int dmax = deg0 > deg1 ? deg0 : deg1;
  int degR = (dmax + 7) & ~7;
  for (int c = 0; c < degR; c += 8){
    unsigned u0[8], u1[8];
    #pragma unroll
    for (int k = 0; k < 8; k++){
      int s = __builtin_amdgcn_readlane(sreg0, c + k);
      u0[k] = (xw + ((size_t)(unsigned)s << 6))[lane];
    }
    #pragma unroll
    for (int k = 0; k < 8; k++){
      int s = __builtin_amdgcn_readlane(sreg1, c + k);
      u1[k] = (xw + ((size_t)(unsigned)s << 6))[lane];
    }
    #pragma unroll
    for (int k = 0; k < 8; k++){
      float q0 = myp0[4*(c+k) + hh];
      float q1 = myp1[4*(c+k) + hh];
      v2f v0 = {blo(u0[k]), bhi(u0[k])};
      v2f v1 = {blo(u1[k]), bhi(u1[k])};
      acc0 += q0 * v0;
      acc1 += q1 * v1;
    }
  }
  #pragma unroll
  for (int m = 1; m < 64; m <<= 1){
    s0x += __shfl_xor(s0x, m); s0y += __shfl_xor(s0y, m);
    s0z += __shfl_xor(s0z, m); s0w += __shfl_xor(s0w, m);
    s1x += __shfl_xor(s1x, m); s1y += __shfl_xor(s1y, m);
    s1z += __shfl_xor(s1z, m); s1w += __shfl_xor(s1w, m);
  }
  s0x += ps0x; s0y += ps0y; s0z += ps0z; s0w += ps0w;
  s1x += ps1x; s1y += ps1y; s1z += ps1z; s1w += ps1w;
  float den0 = (hh < 2 ? (hh == 0 ? s0x : s0y) : (hh == 2 ? s0z : s0w)) + 1e-16f;
  float den1 = (hh < 2 ? (hh == 0 ? s1x : s1y) : (hh == 2 ? s1z : s1w)) + 1e-16f;
  float rden0 = 1.f / den0, rden1 = 1.f / den1;
  int ch = 2*lane;
  float2 blv = *(const float2*)(bl + ch);
  float o00 = acc0.x*rden0 + blv.x, o01 = acc0.y*rden0 + blv.y;
  float o10 = acc1.x*rden1 + blv.x, o11 = acc1.y*rden1 + blv.y;
  float su0 = o00 + o01, sq0 = o00*o00 + o01*o01;
  float su1 = o10 + o11, sq1 = o10*o10 + o11*o11;
  #pragma unroll
  for (int m = 1; m < 64; m <<= 1){
    su0 += __shfl_xor(su0, m); sq0 += __shfl_xor(sq0, m);
    su1 += __shfl_xor(su1, m); sq1 += __shfl_xor(sq1, m);
  }
  float mu0 = su0*(1.f/128.f), mu1 = su1*(1.f/128.f);
  float var0 = sq0*(1.f/128.f) - mu0*mu0; var0 = var0 > 0.f ? var0 : 0.f;
  float var1 = sq1*(1.f/128.f) - mu1*mu1; var1 = var1 > 0.f ? var1 : 0.f;
  float inv0 = rsqrtf(var0 + 1e-5f), inv1 = rsqrtf(var1 + 1e-5f);
  float2 gv  = *(const float2*)(lng + ch);
  float2 bv2 = *(const float2*)(lnb + ch);
  float2 rv0 = *(const float2*)(h + (size_t)n0*128 + ch);
  float2 rv1 = *(const float2*)(h + (size_t)n1*128 + ch);
  o00 = (o00-mu0)*inv0*gv.x + bv2.x + cr0 + rv0.x;
  o01 = (o01-mu0)*inv0*gv.y + bv2.y + cr0 + rv0.y;
  o10 = (o10-mu1)*inv1*gv.x + bv2.x + cr1 + rv1.x;
  o11 = (o11-mu1)*inv1*gv.y + bv2.y + cr1 + rv1.y;
  *(float2*)(&h[(size_t)n0*128 + ch]) = make_float2(o00, o01);
  *(float2*)(&h[(size_t)n1*128 + ch]) = make_float2(o10, o11);
  *(unsigned*)(&hb[(size_t)n0*128 + ch]) = ((unsigned)f2b(o01) << 16) | f2b(o00);
  *(unsigned*)(&hb[(size_t)n1*128 + ch]) = ((unsigned)f2b(o11) << 16) | f2b(o10);
}

// ---------------- pooling: one block per graph, atomic-free ----------------
__global__ __launch_bounds__(256) void k_pool(
    const float* __restrict__ h, float* __restrict__ gate,
    const int* __restrict__ start, float* __restrict__ out)
{
  __shared__ float red[4];
  __shared__ float sbc;
  __shared__ float4 accs[8][32];
  int b = blockIdx.x;
  int s0 = start[b], s1 = start[b+1];
  int tid = threadIdx.x, lane = tid & 63, wave = tid >> 6;
  float m = -3.0e38f;
  for (int i = s0 + tid; i < s1; i += 256) m = fmaxf(m, gate[i]);
  #pragma unroll
  for (int k = 1; k < 64; k <<= 1) m = fmaxf(m, __shfl_xor(m, k));
  if (lane == 0) red[wave] = m;
  __syncthreads();
  if (tid == 0) sbc = fmaxf(fmaxf(red[0],red[1]), fmaxf(red[2],red[3]));
  __syncthreads();
  float gm = sbc;
  __syncthreads();
  float s = 0.f;
  for (int i = s0 + tid; i < s1; i += 256){
    float p = __expf(gate[i] - gm);
    gate[i] = p;
    s += p;
  }
  #pragma unroll
  for (int k = 1; k < 64; k <<= 1) s += __shfl_xor(s, k);
  if (lane == 0) red[wave] = s;
  __syncthreads();
  if (tid == 0) sbc = red[0]+red[1]+red[2]+red[3];
  __syncthreads();
  float inv = 1.f / (sbc + 1e-16f);
  int c4 = (tid & 31) * 4;
  int g  = tid >> 5;
  float4 acc = make_float4(0.f,0.f,0.f,0.f);
  for (int i = s0 + g; i < s1; i += 8){
    float p = gate[i];
    float4 hv = *(const float4*)(h + (size_t)i*128 + c4);
    acc.x = fmaf(p,hv.x,acc.x); acc.y = fmaf(p,hv.y,acc.y);
    acc.z = fmaf(p,hv.z,acc.z); acc.w = fmaf(p,hv.w,acc.w);
  }
  accs[g][tid & 31] = acc;
  __syncthreads();
  if (g == 0){
    float4 t = acc;
    #pragma unroll
    for (int k = 1; k < 8; k++){
      float4 o = accs[k][tid & 31];
      t.x += o.x; t.y += o.y; t.z += o.z; t.w += o.w;
    }
    t.x *= inv; t.y *= inv; t.z *= inv; t.w *= inv;
    *(float4*)(out + b*128 + c4) = t;
  }
}

extern "C" void kernel_launch(void* const* d_in, const int* in_sizes, int n_in,
                              void* d_out, int out_size, void* d_ws, size_t ws_size,
                              hipStream_t stream){
  (void)in_sizes; (void)n_in; (void)out_size; (void)ws_size;
  const float* x    = (const float*)d_in[0];
  const float* ea   = (const float*)d_in[1];
  const float* Win  = (const float*)d_in[2];
  const float* b_in = (const float*)d_in[3];
  const float* We1  = (const float*)d_in[4];
  const float* be1  = (const float*)d_in[5];
  const float* We2  = (const float*)d_in[6];
  const float* be2  = (const float*)d_in[7];
  const float* Wl   = (const float*)d_in[8];
  const float* a_src= (const float*)d_in[9];
  const float* a_dst= (const float*)d_in[10];
  const float* bl   = (const float*)d_in[11];
  const float* lng  = (const float*)d_in[12];
  const float* lnb  = (const float*)d_in[13];
  const float* Wg1  = (const float*)d_in[14];
  const float* bg1  = (const float*)d_in[15];
  const float* Wg2  = (const float*)d_in[16];
  const float* bg2  = (const float*)d_in[17];
  const int*   ei   = (const int*)d_in[18];
  const int*   batch= (const int*)d_in[19];
  float* out = (float*)d_out;

  char* w = (char*)d_ws;
  auto alloc = [&](size_t bytes){ char* p = w; w += (bytes + 255) & ~(size_t)255; return p; };
  float* h    = (float*)alloc((size_t)N_NODES*128*4);
  unsigned short* hb  = (unsigned short*)alloc((size_t)N_NODES*128*2);
  unsigned short* xpb = (unsigned short*)alloc((size_t)N_NODES*128*2);
  float* asn  = (float*)alloc((size_t)N_NODES*4*4);
  float* adn  = (float*)alloc((size_t)N_NODES*4*4);
  float* crit = (float*)alloc((size_t)N_NODES*4);
  int*   cnt  = (int*)alloc((size_t)N_NODES*4);
  int*   incl = (int*)alloc((size_t)N_NODES*4);
  int*   part = (int*)alloc(256*4);
  int*   off  = (int*)alloc((size_t)(N_NODES+1)*4);
  int*   rank = (int*)alloc((size_t)N_EDGES*4);
  int2*  es   = (int2*)alloc((size_t)N_EDGES*8);
  float* gate = (float*)alloc((size_t)N_NODES*4);
  int*   start= (int*)alloc((size_t)(N_B+1)*4);
  unsigned short* WinT = (unsigned short*)alloc((size_t)128*128*2);
  unsigned short* WlT  = (unsigned short*)alloc((size_t)4*144*128*2);
  unsigned short* Wg1T = (unsigned short*)alloc((size_t)64*128*2);

  int nb_n = (N_NODES + 255)/256;   // 196
  int nb_a = 6250;                  // k_aggr: 8 nodes/block exact
  int nb_g = (N_NODES + 63)/64;     // 782
  int nb_c = (98304 + 255)/256;     // 384
  int nb_4e = (200000 + 255)/256;   // 782

  k_conv<<<nb_c,256,0,stream>>>(Win, Wl, a_src, a_dst, Wg1, WinT, WlT, Wg1T);
  k_setup<<<nb_n,256,0,stream>>>(batch, start, cnt);
  k_hist<<<nb_4e,256,0,stream>>>(ei, cnt, rank);
  k_mgemm<8,0,true><<<nb_g,256,0,stream>>>((const void*)x, WinT, b_in, h, hb,
                                           nullptr, nullptr, nullptr, nullptr, nullptr, nullptr);
  k_scan1<<<nb_n,256,0,stream>>>(cnt, incl, part);
  k_scan23<<<nb_n,256,0,stream>>>(cnt, incl, part, off);
  k_fill<<<nb_4e,256,0,stream>>>(ea, We1, be1, We2, be2, ei, off, rank, es);
  for (int l = 0; l < 4; l++){
    k_mgemm<9,1,false><<<nb_g,256,0,stream>>>((const void*)hb, WlT + (size_t)l*144*128, nullptr,
                                              nullptr, nullptr, xpb, asn, adn,
                                              nullptr, nullptr, nullptr);
    if (l == 0)
      k_aggr<true><<<nb_a,256,0,stream>>>(xpb, asn, adn, off, es,
                                          bl + l*128, lng + l*128, lnb + l*128, crit, h, hb);
    else
      k_aggr<false><<<nb_a,256,0,stream>>>(xpb, asn, adn, off, es,
                                           bl + l*128, lng + l*128, lnb + l*128, crit, h, hb);
  }
  k_mgemm<4,2,false><<<nb_g,256,0,stream>>>((const void*)hb, Wg1T, bg1, nullptr, nullptr,
                                            nullptr, nullptr, nullptr, Wg2, bg2, gate);
  k_pool<<<N_B,256,0,stream>>>(h, gate, start, out);
}

// Round 9
// 475.765 us; speedup vs baseline: 1.0318x; 1.0318x over previous
//
#include <hip/hip_runtime.h>
#include <math.h>

#define N_NODES 50000
#define N_EDGES 800000
#define N_B     64

typedef __attribute__((ext_vector_type(8))) short v8s;
typedef __attribute__((ext_vector_type(4))) float v4f;

__device__ __forceinline__ float lrelu(float x){ return x > 0.f ? x : 0.2f*x; }
__device__ __forceinline__ unsigned short f2b(float f){   // fp32 -> bf16 RNE
  unsigned u = __float_as_uint(f);
  return (unsigned short)((u + 0x7fffu + ((u >> 16) & 1u)) >> 16);
}
__device__ __forceinline__ float blo(unsigned u){ return __uint_as_float(u << 16); }
__device__ __forceinline__ float bhi(unsigned u){ return __uint_as_float(u & 0xffff0000u); }

// ---------------- conversion: weights -> transposed bf16 (+fused attn cols) ----------------
__global__ void k_conv(const float* __restrict__ Win, const float* __restrict__ Wl,
                       const float* __restrict__ a_src, const float* __restrict__ a_dst,
                       const float* __restrict__ Wg1,
                       unsigned short* __restrict__ WinT, unsigned short* __restrict__ WlT,
                       unsigned short* __restrict__ Wg1T){
  int i = blockIdx.x*256 + threadIdx.x;
  if (i < 16384){
    int n = i >> 7, k = i & 127;
    WinT[n*128+k] = f2b(Win[k*128+n]);
    return;
  }
  i -= 16384;
  if (i < 65536){
    int l = i >> 14, n = (i >> 7) & 127, k = i & 127;
    WlT[l*144*128 + n*128 + k] = f2b(Wl[l*16384 + k*128 + n]);
    return;
  }
  i -= 65536;
  if (i < 4096){
    int l = i >> 10, k = (i >> 3) & 127, t = i & 7;
    int hh = t & 3, sd = t >> 2;
    const float* av = (sd ? a_dst : a_src) + l*128 + hh*32;
    const float* wr = Wl + l*16384 + k*128 + hh*32;
    float s = 0.f;
    #pragma unroll
    for (int c = 0; c < 32; c++) s = fmaf(wr[c], av[c], s);
    WlT[l*144*128 + (128 + sd*4 + hh)*128 + k] = f2b(s);
    return;
  }
  i -= 4096;
  if (i < 4096){
    int l = i >> 10, r = (i >> 7) & 7, k = i & 127;
    WlT[l*144*128 + (136+r)*128 + k] = 0;
    return;
  }
  i -= 4096;
  if (i < 8192){
    int n = i >> 7, k = i & 127;
    Wg1T[n*128+k] = f2b(Wg1[k*64+n]);
  }
}

// ---------------- setup: zero cnt + graph boundaries (batch sorted) ----------------
__global__ void k_setup(const int* __restrict__ batch, int* __restrict__ start,
                        int* __restrict__ cnt){
  int i = blockIdx.x*256 + threadIdx.x;
  if (i >= N_NODES) return;
  cnt[i] = 0;
  int b = batch[i];
  int bp = (i == 0) ? -1 : batch[i-1];
  for (int j = bp+1; j <= b; j++) start[j] = i;
  if (i == N_NODES-1){
    for (int j = b+1; j <= N_B; j++) start[j] = N_NODES;
  }
}

// ---------------- degree histogram + per-edge rank (atomic returns old count) ----------------
__global__ void k_hist(const int* __restrict__ ei, int* __restrict__ cnt, int* __restrict__ rank){
  int t = blockIdx.x*256 + threadIdx.x;
  if (t >= 200000) return;
  #pragma unroll
  for (int r = 0; r < 4; r++){
    int e = t + r*200000;
    int d = ei[N_EDGES + e];
    rank[e] = atomicAdd(&cnt[d], 1);
  }
}

// ---------------- scan1: per-block inclusive scan ----------------
__global__ void k_scan1(const int* __restrict__ cnt, int* __restrict__ incl, int* __restrict__ part){
  __shared__ int sh[256];
  int tid = threadIdx.x, i = blockIdx.x*256 + tid;
  int v = (i < N_NODES) ? cnt[i] : 0;
  sh[tid] = v; __syncthreads();
  for (int off = 1; off < 256; off <<= 1){
    int t = (tid >= off) ? sh[tid-off] : 0;
    __syncthreads();
    sh[tid] += t; __syncthreads();
  }
  if (i < N_NODES) incl[i] = sh[tid];
  if (tid == 255) part[blockIdx.x] = sh[255];
}
// ---------------- scan23: each block reduces part[0..blockIdx) then writes off ----------------
__global__ void k_scan23(const int* __restrict__ cnt, const int* __restrict__ incl,
                         const int* __restrict__ part, int* __restrict__ off){
  __shared__ int red[4];
  __shared__ int bsum;
  int tid = threadIdx.x, lane = tid & 63, wave = tid >> 6;
  int v = (tid < (int)blockIdx.x) ? part[tid] : 0;   // 196 blocks < 256 threads
  #pragma unroll
  for (int m = 1; m < 64; m <<= 1) v += __shfl_xor(v, m);
  if (lane == 0) red[wave] = v;
  __syncthreads();
  if (tid == 0) bsum = red[0]+red[1]+red[2]+red[3];
  __syncthreads();
  int i = blockIdx.x*256 + tid;
  if (i >= N_NODES) return;
  int e = incl[i] - cnt[i] + bsum;
  off[i] = e;
  if (i == N_NODES-1) off[N_NODES] = e + cnt[i];
}

// ---------------- CSR fill + edge MLP scalar (atomic-free, single 8B scatter) ----------------
__global__ void k_fill(const float* __restrict__ ea, const float* __restrict__ We1,
                       const float* __restrict__ be1, const float* __restrict__ We2,
                       const float* __restrict__ be2, const int* __restrict__ ei,
                       const int* __restrict__ off, const int* __restrict__ rank,
                       int2* __restrict__ es){
  __shared__ float w0[16], w1[16], bb[16], w2s[16];
  __shared__ float b2s;
  int tid = threadIdx.x;
  if (tid < 16){
    w0[tid] = We1[tid]; w1[tid] = We1[16+tid]; bb[tid] = be1[tid];
    w2s[tid] = 0.25f*(We2[tid*4]+We2[tid*4+1]+We2[tid*4+2]+We2[tid*4+3]);
  }
  if (tid == 0) b2s = 0.25f*(be2[0]+be2[1]+be2[2]+be2[3]);
  __syncthreads();
  int t = blockIdx.x*256 + tid;
  if (t >= 200000) return;
  #pragma unroll
  for (int r = 0; r < 4; r++){
    int e = t + r*200000;
    float a0 = ea[2*e], a1 = ea[2*e+1];
    float s = b2s;
    #pragma unroll
    for (int j = 0; j < 16; j++){
      float v = fmaf(a0, w0[j], fmaf(a1, w1[j], bb[j]));
      v = v > 0.f ? v : 0.f;
      s = fmaf(v, w2s[j], s);
    }
    int d = ei[N_EDGES + e];
    int p = off[d] + rank[e];
    es[p] = make_int2(ei[e], __float_as_int(s));
  }
}

// ---------------- MFMA GEMM (AF32: A is fp32, converted during staging) ----------------
template<int NT, int MODE, bool AF32>
__global__ __launch_bounds__(256) void k_mgemm(
    const void* __restrict__ A, const unsigned short* __restrict__ Bt,
    const float* __restrict__ bias,
    float* __restrict__ h, unsigned short* __restrict__ hb,
    unsigned short* __restrict__ xpb, float* __restrict__ asn, float* __restrict__ adn,
    const float* __restrict__ Wg2, const float* __restrict__ bg2, float* __restrict__ gate)
{
  __shared__ __attribute__((aligned(16))) unsigned short Bs[NT*16][136];
  __shared__ __attribute__((aligned(16))) unsigned short As[4][16][136];
  int tid = threadIdx.x, wave = tid >> 6, lane = tid & 63;
  int l15 = lane & 15, quad = lane >> 4;
  int rbase = blockIdx.x * 64;
  for (int id = tid; id < NT*16*16; id += 256){
    int r = id >> 4, ch = id & 15;
    *(v8s*)&Bs[r][ch*8] = *(const v8s*)(Bt + r*128 + ch*8);
  }
  for (int id = tid; id < 64*16; id += 256){
    int r = id >> 4, ch = id & 15;
    int gr = rbase + r;
    v8s v = {0,0,0,0,0,0,0,0};
    if (gr < N_NODES){
      if (AF32){
        const float* Af = (const float*)A + (size_t)gr*128 + ch*8;
        float4 va = *(const float4*)Af;
        float4 vb = *(const float4*)(Af + 4);
        v[0]=(short)f2b(va.x); v[1]=(short)f2b(va.y); v[2]=(short)f2b(va.z); v[3]=(short)f2b(va.w);
        v[4]=(short)f2b(vb.x); v[5]=(short)f2b(vb.y); v[6]=(short)f2b(vb.z); v[7]=(short)f2b(vb.w);
      } else {
        v = *(const v8s*)((const unsigned short*)A + (size_t)gr*128 + ch*8);
      }
    }
    *(v8s*)&As[r >> 4][r & 15][ch*8] = v;
  }
  __syncthreads();
  v4f acc[NT];
  #pragma unroll
  for (int t = 0; t < NT; t++) acc[t] = (v4f){0.f,0.f,0.f,0.f};
  #pragma unroll
  for (int kb = 0; kb < 4; kb++){
    v8s a = *(v8s*)&As[wave][l15][kb*32 + quad*8];
    #pragma unroll
    for (int ct = 0; ct < NT; ct++){
      v8s b = *(v8s*)&Bs[ct*16 + l15][kb*32 + quad*8];
      acc[ct] = __builtin_amdgcn_mfma_f32_16x16x32_bf16(a, b, acc[ct], 0, 0, 0);
    }
  }
  int row0 = rbase + wave*16 + quad*4;
  if (MODE == 0){
    #pragma unroll
    for (int ct = 0; ct < 8; ct++){
      float bcol = bias[ct*16 + l15];
      #pragma unroll
      for (int r = 0; r < 4; r++){
        int gr = row0 + r;
        if (gr < N_NODES){
          float v = acc[ct][r] + bcol;
          h[(size_t)gr*128 + ct*16 + l15] = v;
          hb[(size_t)gr*128 + ct*16 + l15] = f2b(v);
        }
      }
    }
  } else if (MODE == 1){
    #pragma unroll
    for (int ct = 0; ct < 8; ct++){
      #pragma unroll
      for (int r = 0; r < 4; r++){
        int gr = row0 + r;
        if (gr < N_NODES) xpb[(size_t)gr*128 + ct*16 + l15] = f2b(acc[ct][r]);
      }
    }
    #pragma unroll
    for (int r = 0; r < 4; r++){
      int gr = row0 + r;
      if (gr < N_NODES){
        float v = acc[NT-1][r];
        if (l15 < 4) asn[gr*4 + l15] = v;
        else if (l15 < 8) adn[gr*4 + (l15-4)] = v;
      }
    }
  } else {
    float part[4] = {0.f,0.f,0.f,0.f};
    #pragma unroll
    for (int ct = 0; ct < NT; ct++){
      float b1 = bias[ct*16 + l15];
      float w2 = Wg2[ct*16 + l15];
      #pragma unroll
      for (int r = 0; r < 4; r++) part[r] = fmaf(tanhf(acc[ct][r] + b1), w2, part[r]);
    }
    #pragma unroll
    for (int m = 1; m < 16; m <<= 1){
      #pragma unroll
      for (int r = 0; r < 4; r++) part[r] += __shfl_xor(part[r], m);
    }
    if (l15 == 0){
      float b2 = bg2[0];
      #pragma unroll
      for (int r = 0; r < 4; r++){
        int gr = row0 + r;
        if (gr < N_NODES) gate[gr] = part[r] + b2;
      }
    }
  }
}

// ---------------- per-node GAT softmax + aggregate + bias + LN + crit + residual ----------------
// v6 (reinstated): 1 node/wave; deg<=64 fast path; 8-deep branch-free gather pipeline.
// TLP is the latency-hider here: 32 VGPR / 4KB LDS keeps occupancy ~68% (2-node
// interleave variant raised VGPR to 44 and LDS to 8KB -> occupancy 47%, REGRESSED).
template<bool CRIT>
__global__ __launch_bounds__(256) void k_aggr(
    const unsigned short* __restrict__ xpb, const float* __restrict__ asn,
    const float* __restrict__ adn, const int* __restrict__ off,
    const int2* __restrict__ es,
    const float* __restrict__ bl, const float* __restrict__ lng,
    const float* __restrict__ lnb, float* __restrict__ crit,
    float* __restrict__ h, unsigned short* __restrict__ hb)
{
  __shared__ float lp[4][256];
  int wave = threadIdx.x >> 6, lane = threadIdx.x & 63;
  int n = blockIdx.x*4 + wave;
  if (n >= N_NODES) return;
  int base = off[n], deg = off[n+1] - base;
  float4 ad4 = *(const float4*)(adn + n*4);
  float4 asf = *(const float4*)(asn + n*4);
  float ex = lrelu(asf.x+ad4.x), ey = lrelu(asf.y+ad4.y);
  float ez = lrelu(asf.z+ad4.z), ew = lrelu(asf.w+ad4.w);
  const unsigned* xw = (const unsigned*)xpb;
  float* myp = &lp[wave][0];
  int hh = lane >> 4;
  float acc0, acc1, sx, sy, sz, sw, cr;
  float psx, psy, psz, psw;

  if (deg <= 64){
    int sreg = 0;
    float e0 = -3.0e38f, e1 = -3.0e38f, e2 = -3.0e38f, e3 = -3.0e38f;
    float cw = 0.f;
    if (lane < deg){
      int2 er = es[base + lane];
      sreg = er.x;
      float4 a = *(const float4*)(asn + sreg*4);
      e0 = lrelu(a.x+ad4.x); e1 = lrelu(a.y+ad4.y);
      e2 = lrelu(a.z+ad4.z); e3 = lrelu(a.w+ad4.w);
      if (CRIT) cw = __int_as_float(er.y);
    }
    float mx = fmaxf(e0,ex), my = fmaxf(e1,ey), mz = fmaxf(e2,ez), mw = fmaxf(e3,ew);
    #pragma unroll
    for (int m = 1; m < 64; m <<= 1){
      mx = fmaxf(mx, __shfl_xor(mx, m)); my = fmaxf(my, __shfl_xor(my, m));
      mz = fmaxf(mz, __shfl_xor(mz, m)); mw = fmaxf(mw, __shfl_xor(mw, m));
      if (CRIT) cw += __shfl_xor(cw, m);
    }
    if (CRIT){ if (lane == 0) crit[n] = cw; cr = cw; }
    else cr = crit[n];
    psx = __expf(ex-mx); psy = __expf(ey-my); psz = __expf(ez-mz); psw = __expf(ew-mw);
    float p0 = 0.f, p1 = 0.f, p2 = 0.f, p3 = 0.f;
    if (lane < deg){
      p0 = __expf(e0-mx); p1 = __expf(e1-my); p2 = __expf(e2-mz); p3 = __expf(e3-mw);
    }
    sx = p0; sy = p1; sz = p2; sw = p3;
    *(float4*)(&myp[4*lane]) = make_float4(p0,p1,p2,p3);
    __threadfence_block();
    float pself = hh < 2 ? (hh == 0 ? psx : psy) : (hh == 2 ? psz : psw);
    unsigned us = (xw + ((size_t)(unsigned)n << 6))[lane];
    acc0 = pself * blo(us); acc1 = pself * bhi(us);
    int degR = (deg + 7) & ~7;
    for (int c = 0; c < degR; c += 8){
      unsigned u[8];
      #pragma unroll
      for (int k = 0; k < 8; k++){
        int s0 = __builtin_amdgcn_readlane(sreg, c + k);
        u[k] = (xw + ((size_t)(unsigned)s0 << 6))[lane];     // SGPR base + lane*4
      }
      #pragma unroll
      for (int k = 0; k < 8; k++){
        float q = myp[4*(c+k) + hh];
        acc0 = fmaf(q, blo(u[k]), acc0);
        acc1 = fmaf(q, bhi(u[k]), acc1);
      }
    }
    __threadfence_block();
  } else {
    // ---- general path (rare): two-pass ----
    float mx = ex, my = ey, mz = ez, mw = ew;
    float cw = 0.f;
    for (int j = lane; j < deg; j += 64){
      int2 er = es[base + j];
      float4 a = *(const float4*)(asn + er.x*4);
      mx = fmaxf(mx, lrelu(a.x+ad4.x)); my = fmaxf(my, lrelu(a.y+ad4.y));
      mz = fmaxf(mz, lrelu(a.z+ad4.z)); mw = fmaxf(mw, lrelu(a.w+ad4.w));
      if (CRIT) cw += __int_as_float(er.y);
    }
    #pragma unroll
    for (int m = 1; m < 64; m <<= 1){
      mx = fmaxf(mx, __shfl_xor(mx, m)); my = fmaxf(my, __shfl_xor(my, m));
      mz = fmaxf(mz, __shfl_xor(mz, m)); mw = fmaxf(mw, __shfl_xor(mw, m));
      if (CRIT) cw += __shfl_xor(cw, m);
    }
    if (CRIT){ if (lane == 0) crit[n] = cw; cr = cw; }
    else cr = crit[n];
    psx = __expf(ex-mx); psy = __expf(ey-my); psz = __expf(ez-mz); psw = __expf(ew-mw);
    float pself = hh < 2 ? (hh == 0 ? psx : psy) : (hh == 2 ? psz : psw);
    unsigned us = (xw + ((size_t)(unsigned)n << 6))[lane];
    acc0 = pself * blo(us); acc1 = pself * bhi(us);
    sx = 0.f; sy = 0.f; sz = 0.f; sw = 0.f;
    for (int j0 = 0; j0 < deg; j0 += 64){
      int clen = deg - j0; if (clen > 64) clen = 64;
      int sreg = 0;
      float p0 = 0.f, p1 = 0.f, p2 = 0.f, p3 = 0.f;
      if (lane < clen){
        sreg = es[base + j0 + lane].x;
        float4 a = *(const float4*)(asn + sreg*4);
        p0 = __expf(lrelu(a.x+ad4.x)-mx);
        p1 = __expf(lrelu(a.y+ad4.y)-my);
        p2 = __expf(lrelu(a.z+ad4.z)-mz);
        p3 = __expf(lrelu(a.w+ad4.w)-mw);
        sx += p0; sy += p1; sz += p2; sw += p3;
      }
      *(float4*)(&myp[4*lane]) = make_float4(p0,p1,p2,p3);
      __threadfence_block();
      int clenR = (clen + 7) & ~7;
      for (int c = 0; c < clenR; c += 8){
        unsigned u[8];
        #pragma unroll
        for (int k = 0; k < 8; k++){
          int s0 = __builtin_amdgcn_readlane(sreg, c + k);
          u[k] = (xw + ((size_t)(unsigned)s0 << 6))[lane];
        }
        #pragma unroll
        for (int k = 0; k < 8; k++){
          float q = myp[4*(c+k) + hh];
          acc0 = fmaf(q, blo(u[k]), acc0);
          acc1 = fmaf(q, bhi(u[k]), acc1);
        }
      }
      __threadfence_block();
    }
  }
  #pragma unroll
  for (int m = 1; m < 64; m <<= 1){
    sx += __shfl_xor(sx, m); sy += __shfl_xor(sy, m);
    sz += __shfl_xor(sz, m); sw += __shfl_xor(sw, m);
  }
  sx += psx; sy += psy; sz += psz; sw += psw;
  float den = (hh < 2 ? (hh == 0 ? sx : sy) : (hh == 2 ? sz : sw)) + 1e-16f;
  float rden = 1.f / den;
  int c0 = 2*lane;
  float2 blv = *(const float2*)(bl + c0);
  float o0 = acc0*rden + blv.x;
  float o1 = acc1*rden + blv.y;
  float su = o0 + o1, sq = o0*o0 + o1*o1;
  #pragma unroll
  for (int m = 1; m < 64; m <<= 1){ su += __shfl_xor(su, m); sq += __shfl_xor(sq, m); }
  float mu  = su * (1.f/128.f);
  float var = sq * (1.f/128.f) - mu*mu; var = var > 0.f ? var : 0.f;
  float inv = rsqrtf(var + 1e-5f);
  float2 rv  = *(const float2*)(h + (size_t)n*128 + c0);
  float2 gv  = *(const float2*)(lng + c0);
  float2 bv2 = *(const float2*)(lnb + c0);
  o0 = (o0-mu)*inv*gv.x + bv2.x + cr + rv.x;
  o1 = (o1-mu)*inv*gv.y + bv2.y + cr + rv.y;
  *(float2*)(&h[(size_t)n*128 + c0]) = make_float2(o0, o1);
  *(unsigned*)(&hb[(size_t)n*128 + c0]) = ((unsigned)f2b(o1) << 16) | f2b(o0);
}

// ---------------- pooling: one block per graph, atomic-free ----------------
__global__ __launch_bounds__(256) void k_pool(
    const float* __restrict__ h, float* __restrict__ gate,
    const int* __restrict__ start, float* __restrict__ out)
{
  __shared__ float red[4];
  __shared__ float sbc;
  __shared__ float4 accs[8][32];
  int b = blockIdx.x;
  int s0 = start[b], s1 = start[b+1];
  int tid = threadIdx.x, lane = tid & 63, wave = tid >> 6;
  float m = -3.0e38f;
  for (int i = s0 + tid; i < s1; i += 256) m = fmaxf(m, gate[i]);
  #pragma unroll
  for (int k = 1; k < 64; k <<= 1) m = fmaxf(m, __shfl_xor(m, k));
  if (lane == 0) red[wave] = m;
  __syncthreads();
  if (tid == 0) sbc = fmaxf(fmaxf(red[0],red[1]), fmaxf(red[2],red[3]));
  __syncthreads();
  float gm = sbc;
  __syncthreads();
  float s = 0.f;
  for (int i = s0 + tid; i < s1; i += 256){
    float p = __expf(gate[i] - gm);
    gate[i] = p;
    s += p;
  }
  #pragma unroll
  for (int k = 1; k < 64; k <<= 1) s += __shfl_xor(s, k);
  if (lane == 0) red[wave] = s;
  __syncthreads();
  if (tid == 0) sbc = red[0]+red[1]+red[2]+red[3];
  __syncthreads();
  float inv = 1.f / (sbc + 1e-16f);
  int c4 = (tid & 31) * 4;
  int g  = tid >> 5;
  float4 acc = make_float4(0.f,0.f,0.f,0.f);
  for (int i = s0 + g; i < s1; i += 8){
    float p = gate[i];
    float4 hv = *(const float4*)(h + (size_t)i*128 + c4);
    acc.x = fmaf(p,hv.x,acc.x); acc.y = fmaf(p,hv.y,acc.y);
    acc.z = fmaf(p,hv.z,acc.z); acc.w = fmaf(p,hv.w,acc.w);
  }
  accs[g][tid & 31] = acc;
  __syncthreads();
  if (g == 0){
    float4 t = acc;
    #pragma unroll
    for (int k = 1; k < 8; k++){
      float4 o = accs[k][tid & 31];
      t.x += o.x; t.y += o.y; t.z += o.z; t.w += o.w;
    }
    t.x *= inv; t.y *= inv; t.z *= inv; t.w *= inv;
    *(float4*)(out + b*128 + c4) = t;
  }
}

extern "C" void kernel_launch(void* const* d_in, const int* in_sizes, int n_in,
                              void* d_out, int out_size, void* d_ws, size_t ws_size,
                              hipStream_t stream){
  (void)in_sizes; (void)n_in; (void)out_size; (void)ws_size;
  const float* x    = (const float*)d_in[0];
  const float* ea   = (const float*)d_in[1];
  const float* Win  = (const float*)d_in[2];
  const float* b_in = (const float*)d_in[3];
  const float* We1  = (const float*)d_in[4];
  const float* be1  = (const float*)d_in[5];
  const float* We2  = (const float*)d_in[6];
  const float* be2  = (const float*)d_in[7];
  const float* Wl   = (const float*)d_in[8];
  const float* a_src= (const float*)d_in[9];
  const float* a_dst= (const float*)d_in[10];
  const float* bl   = (const float*)d_in[11];
  const float* lng  = (const float*)d_in[12];
  const float* lnb  = (const float*)d_in[13];
  const float* Wg1  = (const float*)d_in[14];
  const float* bg1  = (const float*)d_in[15];
  const float* Wg2  = (const float*)d_in[16];
  const float* bg2  = (const float*)d_in[17];
  const int*   ei   = (const int*)d_in[18];
  const int*   batch= (const int*)d_in[19];
  float* out = (float*)d_out;

  char* w = (char*)d_ws;
  auto alloc = [&](size_t bytes){ char* p = w; w += (bytes + 255) & ~(size_t)255; return p; };
  float* h    = (float*)alloc((size_t)N_NODES*128*4);
  unsigned short* hb  = (unsigned short*)alloc((size_t)N_NODES*128*2);
  unsigned short* xpb = (unsigned short*)alloc((size_t)N_NODES*128*2);
  float* asn  = (float*)alloc((size_t)N_NODES*4*4);
  float* adn  = (float*)alloc((size_t)N_NODES*4*4);
  float* crit = (float*)alloc((size_t)N_NODES*4);
  int*   cnt  = (int*)alloc((size_t)N_NODES*4);
  int*   incl = (int*)alloc((size_t)N_NODES*4);
  int*   part = (int*)alloc(256*4);
  int*   off  = (int*)alloc((size_t)(N_NODES+1)*4);
  int*   rank = (int*)alloc((size_t)N_EDGES*4);
  int2*  es   = (int2*)alloc((size_t)N_EDGES*8);
  float* gate = (float*)alloc((size_t)N_NODES*4);
  int*   start= (int*)alloc((size_t)(N_B+1)*4);
  unsigned short* WinT = (unsigned short*)alloc((size_t)128*128*2);
  unsigned short* WlT  = (unsigned short*)alloc((size_t)4*144*128*2);
  unsigned short* Wg1T = (unsigned short*)alloc((size_t)64*128*2);

  int nb_n = (N_NODES + 255)/256;   // 196
  int nb_w = (N_NODES + 3)/4;       // 12500 (one wave per node)
  int nb_g = (N_NODES + 63)/64;     // 782
  int nb_c = (98304 + 255)/256;     // 384
  int nb_4e = (200000 + 255)/256;   // 782

  k_conv<<<nb_c,256,0,stream>>>(Win, Wl, a_src, a_dst, Wg1, WinT, WlT, Wg1T);
  k_setup<<<nb_n,256,0,stream>>>(batch, start, cnt);
  k_hist<<<nb_4e,256,0,stream>>>(ei, cnt, rank);
  k_mgemm<8,0,true><<<nb_g,256,0,stream>>>((const void*)x, WinT, b_in, h, hb,
                                           nullptr, nullptr, nullptr, nullptr, nullptr, nullptr);
  k_scan1<<<nb_n,256,0,stream>>>(cnt, incl, part);
  k_scan23<<<nb_n,256,0,stream>>>(cnt, incl, part, off);
  k_fill<<<nb_4e,256,0,stream>>>(ea, We1, be1, We2, be2, ei, off, rank, es);
  for (int l = 0; l < 4; l++){
    k_mgemm<9,1,false><<<nb_g,256,0,stream>>>((const void*)hb, WlT + (size_t)l*144*128, nullptr,
                                              nullptr, nullptr, xpb, asn, adn,
                                              nullptr, nullptr, nullptr);
    if (l == 0)
      k_aggr<true><<<nb_w,256,0,stream>>>(xpb, asn, adn, off, es,
                                          bl + l*128, lng + l*128, lnb + l*128, crit, h, hb);
    else
      k_aggr<false><<<nb_w,256,0,stream>>>(xpb, asn, adn, off, es,
                                           bl + l*128, lng + l*128, lnb + l*128, crit, h, hb);
  }
  k_mgemm<4,2,false><<<nb_g,256,0,stream>>>((const void*)hb, Wg1T, bg1, nullptr, nullptr,
                                            nullptr, nullptr, nullptr, Wg2, bg2, gate);
  k_pool<<<N_B,256,0,stream>>>(h, gate, start, out);
}

// Round 10
// 440.059 us; speedup vs baseline: 1.1155x; 1.0811x over previous
//
#include <hip/hip_runtime.h>
#include <math.h>

#define N_NODES 50000
#define N_EDGES 800000
#define N_B     64

typedef __attribute__((ext_vector_type(8))) short v8s;
typedef __attribute__((ext_vector_type(4))) float v4f;
typedef __attribute__((ext_vector_type(2))) float v2f;

__device__ __forceinline__ float lrelu(float x){ return x > 0.f ? x : 0.2f*x; }
__device__ __forceinline__ unsigned short f2b(float f){   // fp32 -> bf16 RNE
  unsigned u = __float_as_uint(f);
  return (unsigned short)((u + 0x7fffu + ((u >> 16) & 1u)) >> 16);
}
__device__ __forceinline__ float blo(unsigned u){ return __uint_as_float(u << 16); }
__device__ __forceinline__ float bhi(unsigned u){ return __uint_as_float(u & 0xffff0000u); }

// ---------------- conv (weights->bf16^T, fused attn cols) + setup (cnt=0, graph bounds) ----------------
__global__ void k_convsetup(const float* __restrict__ Win, const float* __restrict__ Wl,
                            const float* __restrict__ a_src, const float* __restrict__ a_dst,
                            const float* __restrict__ Wg1, const int* __restrict__ batch,
                            unsigned short* __restrict__ WinT, unsigned short* __restrict__ WlT,
                            unsigned short* __restrict__ Wg1T, int* __restrict__ start,
                            int* __restrict__ cnt){
  if (blockIdx.x >= 384){                             // ---- setup part ----
    int i = (blockIdx.x - 384)*256 + threadIdx.x;
    if (i >= N_NODES) return;
    cnt[i] = 0;
    int b = batch[i];
    int bp = (i == 0) ? -1 : batch[i-1];
    for (int j = bp+1; j <= b; j++) start[j] = i;
    if (i == N_NODES-1){
      for (int j = b+1; j <= N_B; j++) start[j] = N_NODES;
    }
    return;
  }
  int i = blockIdx.x*256 + threadIdx.x;
  if (i < 16384){
    int n = i >> 7, k = i & 127;
    WinT[n*128+k] = f2b(Win[k*128+n]);
    return;
  }
  i -= 16384;
  if (i < 65536){
    int l = i >> 14, n = (i >> 7) & 127, k = i & 127;
    WlT[l*144*128 + n*128 + k] = f2b(Wl[l*16384 + k*128 + n]);
    return;
  }
  i -= 65536;
  if (i < 4096){
    int l = i >> 10, k = (i >> 3) & 127, t = i & 7;
    int hh = t & 3, sd = t >> 2;
    const float* av = (sd ? a_dst : a_src) + l*128 + hh*32;
    const float* wr = Wl + l*16384 + k*128 + hh*32;
    float s = 0.f;
    #pragma unroll
    for (int c = 0; c < 32; c++) s = fmaf(wr[c], av[c], s);
    WlT[l*144*128 + (128 + sd*4 + hh)*128 + k] = f2b(s);
    return;
  }
  i -= 4096;
  if (i < 4096){
    int l = i >> 10, r = (i >> 7) & 7, k = i & 127;
    WlT[l*144*128 + (136+r)*128 + k] = 0;
    return;
  }
  i -= 4096;
  if (i < 8192){
    int n = i >> 7, k = i & 127;
    Wg1T[n*128+k] = f2b(Wg1[k*64+n]);
  }
}

// ---------------- degree histogram + per-edge rank (atomic returns old count) ----------------
__global__ void k_hist(const int* __restrict__ ei, int* __restrict__ cnt, int* __restrict__ rank){
  int t = blockIdx.x*256 + threadIdx.x;
  if (t >= 200000) return;
  #pragma unroll
  for (int r = 0; r < 4; r++){
    int e = t + r*200000;
    int d = ei[N_EDGES + e];
    rank[e] = atomicAdd(&cnt[d], 1);
  }
}

// ---------------- scan1: per-block inclusive scan ----------------
__global__ void k_scan1(const int* __restrict__ cnt, int* __restrict__ incl, int* __restrict__ part){
  __shared__ int sh[256];
  int tid = threadIdx.x, i = blockIdx.x*256 + tid;
  int v = (i < N_NODES) ? cnt[i] : 0;
  sh[tid] = v; __syncthreads();
  for (int off = 1; off < 256; off <<= 1){
    int t = (tid >= off) ? sh[tid-off] : 0;
    __syncthreads();
    sh[tid] += t; __syncthreads();
  }
  if (i < N_NODES) incl[i] = sh[tid];
  if (tid == 255) part[blockIdx.x] = sh[255];
}
// ---------------- scan23: each block reduces part[0..blockIdx) then writes off ----------------
__global__ void k_scan23(const int* __restrict__ cnt, const int* __restrict__ incl,
                         const int* __restrict__ part, int* __restrict__ off){
  __shared__ int red[4];
  __shared__ int bsum;
  int tid = threadIdx.x, lane = tid & 63, wave = tid >> 6;
  int v = (tid < (int)blockIdx.x) ? part[tid] : 0;   // 196 blocks < 256 threads
  #pragma unroll
  for (int m = 1; m < 64; m <<= 1) v += __shfl_xor(v, m);
  if (lane == 0) red[wave] = v;
  __syncthreads();
  if (tid == 0) bsum = red[0]+red[1]+red[2]+red[3];
  __syncthreads();
  int i = blockIdx.x*256 + tid;
  if (i >= N_NODES) return;
  int e = incl[i] - cnt[i] + bsum;
  off[i] = e;
  if (i == N_NODES-1) off[N_NODES] = e + cnt[i];
}

// ---------------- CSR fill + edge MLP scalar (atomic-free, single 8B scatter) ----------------
__global__ void k_fill(const float* __restrict__ ea, const float* __restrict__ We1,
                       const float* __restrict__ be1, const float* __restrict__ We2,
                       const float* __restrict__ be2, const int* __restrict__ ei,
                       const int* __restrict__ off, const int* __restrict__ rank,
                       int2* __restrict__ es){
  __shared__ float w0[16], w1[16], bb[16], w2s[16];
  __shared__ float b2s;
  int tid = threadIdx.x;
  if (tid < 16){
    w0[tid] = We1[tid]; w1[tid] = We1[16+tid]; bb[tid] = be1[tid];
    w2s[tid] = 0.25f*(We2[tid*4]+We2[tid*4+1]+We2[tid*4+2]+We2[tid*4+3]);
  }
  if (tid == 0) b2s = 0.25f*(be2[0]+be2[1]+be2[2]+be2[3]);
  __syncthreads();
  int t = blockIdx.x*256 + tid;
  if (t >= 200000) return;
  #pragma unroll
  for (int r = 0; r < 4; r++){
    int e = t + r*200000;
    float a0 = ea[2*e], a1 = ea[2*e+1];
    float s = b2s;
    #pragma unroll
    for (int j = 0; j < 16; j++){
      float v = fmaf(a0, w0[j], fmaf(a1, w1[j], bb[j]));
      v = v > 0.f ? v : 0.f;
      s = fmaf(v, w2s[j], s);
    }
    int d = ei[N_EDGES + e];
    int p = off[d] + rank[e];
    es[p] = make_int2(ei[e], __float_as_int(s));
  }
}

// ---------------- MFMA GEMM (A always fp32 h/x, converted during staging) ----------------
template<int NT, int MODE>
__global__ __launch_bounds__(256) void k_mgemm(
    const float* __restrict__ A, const unsigned short* __restrict__ Bt,
    const float* __restrict__ bias,
    float* __restrict__ h,
    unsigned short* __restrict__ xpb, float* __restrict__ asn, float* __restrict__ adn,
    const float* __restrict__ Wg2, const float* __restrict__ bg2, float* __restrict__ gate)
{
  __shared__ __attribute__((aligned(16))) unsigned short Bs[NT*16][136];
  __shared__ __attribute__((aligned(16))) unsigned short As[4][16][136];
  int tid = threadIdx.x, wave = tid >> 6, lane = tid & 63;
  int l15 = lane & 15, quad = lane >> 4;
  int rbase = blockIdx.x * 64;
  for (int id = tid; id < NT*16*16; id += 256){
    int r = id >> 4, ch = id & 15;
    *(v8s*)&Bs[r][ch*8] = *(const v8s*)(Bt + r*128 + ch*8);
  }
  for (int id = tid; id < 64*16; id += 256){
    int r = id >> 4, ch = id & 15;
    int gr = rbase + r;
    v8s v = {0,0,0,0,0,0,0,0};
    if (gr < N_NODES){
      const float* Af = A + (size_t)gr*128 + ch*8;
      float4 va = *(const float4*)Af;
      float4 vb = *(const float4*)(Af + 4);
      v[0]=(short)f2b(va.x); v[1]=(short)f2b(va.y); v[2]=(short)f2b(va.z); v[3]=(short)f2b(va.w);
      v[4]=(short)f2b(vb.x); v[5]=(short)f2b(vb.y); v[6]=(short)f2b(vb.z); v[7]=(short)f2b(vb.w);
    }
    *(v8s*)&As[r >> 4][r & 15][ch*8] = v;
  }
  __syncthreads();
  v4f acc[NT];
  #pragma unroll
  for (int t = 0; t < NT; t++) acc[t] = (v4f){0.f,0.f,0.f,0.f};
  #pragma unroll
  for (int kb = 0; kb < 4; kb++){
    v8s a = *(v8s*)&As[wave][l15][kb*32 + quad*8];
    #pragma unroll
    for (int ct = 0; ct < NT; ct++){
      v8s b = *(v8s*)&Bs[ct*16 + l15][kb*32 + quad*8];
      acc[ct] = __builtin_amdgcn_mfma_f32_16x16x32_bf16(a, b, acc[ct], 0, 0, 0);
    }
  }
  int row0 = rbase + wave*16 + quad*4;
  if (MODE == 0){
    #pragma unroll
    for (int ct = 0; ct < 8; ct++){
      float bcol = bias[ct*16 + l15];
      #pragma unroll
      for (int r = 0; r < 4; r++){
        int gr = row0 + r;
        if (gr < N_NODES) h[(size_t)gr*128 + ct*16 + l15] = acc[ct][r] + bcol;
      }
    }
  } else if (MODE == 1){
    #pragma unroll
    for (int ct = 0; ct < 8; ct++){
      #pragma unroll
      for (int r = 0; r < 4; r++){
        int gr = row0 + r;
        if (gr < N_NODES) xpb[(size_t)gr*128 + ct*16 + l15] = f2b(acc[ct][r]);
      }
    }
    #pragma unroll
    for (int r = 0; r < 4; r++){
      int gr = row0 + r;
      if (gr < N_NODES){
        float v = acc[NT-1][r];
        if (l15 < 4) asn[gr*4 + l15] = v;
        else if (l15 < 8) adn[gr*4 + (l15-4)] = v;
      }
    }
  } else {
    float part[4] = {0.f,0.f,0.f,0.f};
    #pragma unroll
    for (int ct = 0; ct < NT; ct++){
      float b1 = bias[ct*16 + l15];
      float w2 = Wg2[ct*16 + l15];
      #pragma unroll
      for (int r = 0; r < 4; r++) part[r] = fmaf(tanhf(acc[ct][r] + b1), w2, part[r]);
    }
    #pragma unroll
    for (int m = 1; m < 16; m <<= 1){
      #pragma unroll
      for (int r = 0; r < 4; r++) part[r] += __shfl_xor(part[r], m);
    }
    if (l15 == 0){
      float b2 = bg2[0];
      #pragma unroll
      for (int r = 0; r < 4; r++){
        int gr = row0 + r;
        if (gr < N_NODES) gate[gr] = part[r] + b2;
      }
    }
  }
}

// ---------------- per-node GAT softmax + aggregate + bias + LN + crit + residual ----------------
// v8: softmax shifted by e_self (wave-uniform, ZERO reduce; self numerator == 1);
// denominator accumulated in-register during the gather loop (every lane reads every
// edge's q from LDS) -> no shuffle reduce for max OR sum. 1 node/wave, 8-deep
// branch-free gather pipeline. TLP hides gather latency: keep VGPR<=32, LDS<=4KB.
template<bool CRIT>
__global__ __launch_bounds__(256) void k_aggr(
    const unsigned short* __restrict__ xpb, const float* __restrict__ asn,
    const float* __restrict__ adn, const int* __restrict__ off,
    const int2* __restrict__ es,
    const float* __restrict__ bl, const float* __restrict__ lng,
    const float* __restrict__ lnb, float* __restrict__ crit,
    float* __restrict__ h)
{
  __shared__ float lp[4][256];
  int wave = threadIdx.x >> 6, lane = threadIdx.x & 63;
  int n = blockIdx.x*4 + wave;
  if (n >= N_NODES) return;
  int base = off[n], deg = off[n+1] - base;
  float4 ad4 = *(const float4*)(adn + n*4);
  float4 asf = *(const float4*)(asn + n*4);
  float ex = lrelu(asf.x+ad4.x), ey = lrelu(asf.y+ad4.y);
  float ez = lrelu(asf.z+ad4.z), ew = lrelu(asf.w+ad4.w);
  const unsigned* xw = (const unsigned*)xpb;
  float* myp = &lp[wave][0];
  int hh = lane >> 4;
  float cr, dsum = 0.f;
  v2f acc;
  unsigned us = (xw + ((size_t)(unsigned)n << 6))[lane];
  acc.x = blo(us); acc.y = bhi(us);                   // self numerator == exp(0) == 1

  if (deg <= 64){
    int sreg = 0;
    float cw = 0.f;
    float p0 = 0.f, p1 = 0.f, p2 = 0.f, p3 = 0.f;
    if (lane < deg){
      int2 er = es[base + lane];
      sreg = er.x;
      float4 a = *(const float4*)(asn + sreg*4);
      p0 = __expf(lrelu(a.x+ad4.x) - ex);
      p1 = __expf(lrelu(a.y+ad4.y) - ey);
      p2 = __expf(lrelu(a.z+ad4.z) - ez);
      p3 = __expf(lrelu(a.w+ad4.w) - ew);
      if (CRIT) cw = __int_as_float(er.y);
    }
    if (CRIT){
      #pragma unroll
      for (int m = 1; m < 64; m <<= 1) cw += __shfl_xor(cw, m);
      if (lane == 0) crit[n] = cw;
      cr = cw;
    } else cr = crit[n];
    *(float4*)(&myp[4*lane]) = make_float4(p0,p1,p2,p3);
    __threadfence_block();
    int degR = (deg + 7) & ~7;
    for (int c = 0; c < degR; c += 8){
      unsigned u[8];
      #pragma unroll
      for (int k = 0; k < 8; k++){
        int s0 = __builtin_amdgcn_readlane(sreg, c + k);
        u[k] = (xw + ((size_t)(unsigned)s0 << 6))[lane];     // SGPR base + lane*4
      }
      #pragma unroll
      for (int k = 0; k < 8; k++){
        float q = myp[4*(c+k) + hh];
        dsum += q;                                           // full denom, no reduce
        v2f v = {blo(u[k]), bhi(u[k])};
        acc += q * v;
      }
    }
    __threadfence_block();
  } else {
    // ---- general path (rare): tile loop; crit pass only in layer 0 ----
    if (CRIT){
      float cw = 0.f;
      for (int j = lane; j < deg; j += 64) cw += __int_as_float(es[base + j].y);
      #pragma unroll
      for (int m = 1; m < 64; m <<= 1) cw += __shfl_xor(cw, m);
      if (lane == 0) crit[n] = cw;
      cr = cw;
    } else cr = crit[n];
    for (int j0 = 0; j0 < deg; j0 += 64){
      int clen = deg - j0; if (clen > 64) clen = 64;
      int sreg = 0;
      float p0 = 0.f, p1 = 0.f, p2 = 0.f, p3 = 0.f;
      if (lane < clen){
        sreg = es[base + j0 + lane].x;
        float4 a = *(const float4*)(asn + sreg*4);
        p0 = __expf(lrelu(a.x+ad4.x) - ex);
        p1 = __expf(lrelu(a.y+ad4.y) - ey);
        p2 = __expf(lrelu(a.z+ad4.z) - ez);
        p3 = __expf(lrelu(a.w+ad4.w) - ew);
      }
      *(float4*)(&myp[4*lane]) = make_float4(p0,p1,p2,p3);
      __threadfence_block();
      int clenR = (clen + 7) & ~7;
      for (int c = 0; c < clenR; c += 8){
        unsigned u[8];
        #pragma unroll
        for (int k = 0; k < 8; k++){
          int s0 = __builtin_amdgcn_readlane(sreg, c + k);
          u[k] = (xw + ((size_t)(unsigned)s0 << 6))[lane];
        }
        #pragma unroll
        for (int k = 0; k < 8; k++){
          float q = myp[4*(c+k) + hh];
          dsum += q;
          v2f v = {blo(u[k]), bhi(u[k])};
          acc += q * v;
        }
      }
      __threadfence_block();
    }
  }
  float rden = 1.f / (dsum + 1.f + 1e-16f);            // +1 = self term
  int c0 = 2*lane;
  float2 blv = *(const float2*)(bl + c0);
  float o0 = acc.x*rden + blv.x;
  float o1 = acc.y*rden + blv.y;
  float su = o0 + o1, sq = o0*o0 + o1*o1;
  #pragma unroll
  for (int m = 1; m < 64; m <<= 1){ su += __shfl_xor(su, m); sq += __shfl_xor(sq, m); }
  float mu  = su * (1.f/128.f);
  float var = sq * (1.f/128.f) - mu*mu; var = var > 0.f ? var : 0.f;
  float inv = rsqrtf(var + 1e-5f);
  float2 rv  = *(const float2*)(h + (size_t)n*128 + c0);
  float2 gv  = *(const float2*)(lng + c0);
  float2 bv2 = *(const float2*)(lnb + c0);
  o0 = (o0-mu)*inv*gv.x + bv2.x + cr + rv.x;
  o1 = (o1-mu)*inv*gv.y + bv2.y + cr + rv.y;
  *(float2*)(&h[(size_t)n*128 + c0]) = make_float2(o0, o1);
}

// ---------------- pooling: one block per graph, atomic-free ----------------
__global__ __launch_bounds__(256) void k_pool(
    const float* __restrict__ h, float* __restrict__ gate,
    const int* __restrict__ start, float* __restrict__ out)
{
  __shared__ float red[4];
  __shared__ float sbc;
  __shared__ float4 accs[8][32];
  int b = blockIdx.x;
  int s0 = start[b], s1 = start[b+1];
  int tid = threadIdx.x, lane = tid & 63, wave = tid >> 6;
  float m = -3.0e38f;
  for (int i = s0 + tid; i < s1; i += 256) m = fmaxf(m, gate[i]);
  #pragma unroll
  for (int k = 1; k < 64; k <<= 1) m = fmaxf(m, __shfl_xor(m, k));
  if (lane == 0) red[wave] = m;
  __syncthreads();
  if (tid == 0) sbc = fmaxf(fmaxf(red[0],red[1]), fmaxf(red[2],red[3]));
  __syncthreads();
  float gm = sbc;
  __syncthreads();
  float s = 0.f;
  for (int i = s0 + tid; i < s1; i += 256){
    float p = __expf(gate[i] - gm);
    gate[i] = p;
    s += p;
  }
  #pragma unroll
  for (int k = 1; k < 64; k <<= 1) s += __shfl_xor(s, k);
  if (lane == 0) red[wave] = s;
  __syncthreads();
  if (tid == 0) sbc = red[0]+red[1]+red[2]+red[3];
  __syncthreads();
  float inv = 1.f / (sbc + 1e-16f);
  int c4 = (tid & 31) * 4;
  int g  = tid >> 5;
  float4 acc = make_float4(0.f,0.f,0.f,0.f);
  for (int i = s0 + g; i < s1; i += 8){
    float p = gate[i];
    float4 hv = *(const float4*)(h + (size_t)i*128 + c4);
    acc.x = fmaf(p,hv.x,acc.x); acc.y = fmaf(p,hv.y,acc.y);
    acc.z = fmaf(p,hv.z,acc.z); acc.w = fmaf(p,hv.w,acc.w);
  }
  accs[g][tid & 31] = acc;
  __syncthreads();
  if (g == 0){
    float4 t = acc;
    #pragma unroll
    for (int k = 1; k < 8; k++){
      float4 o = accs[k][tid & 31];
      t.x += o.x; t.y += o.y; t.z += o.z; t.w += o.w;
    }
    t.x *= inv; t.y *= inv; t.z *= inv; t.w *= inv;
    *(float4*)(out + b*128 + c4) = t;
  }
}

extern "C" void kernel_launch(void* const* d_in, const int* in_sizes, int n_in,
                              void* d_out, int out_size, void* d_ws, size_t ws_size,
                              hipStream_t stream){
  (void)in_sizes; (void)n_in; (void)out_size; (void)ws_size;
  const float* x    = (const float*)d_in[0];
  const float* ea   = (const float*)d_in[1];
  const float* Win  = (const float*)d_in[2];
  const float* b_in = (const float*)d_in[3];
  const float* We1  = (const float*)d_in[4];
  const float* be1  = (const float*)d_in[5];
  const float* We2  = (const float*)d_in[6];
  const float* be2  = (const float*)d_in[7];
  const float* Wl   = (const float*)d_in[8];
  const float* a_src= (const float*)d_in[9];
  const float* a_dst= (const float*)d_in[10];
  const float* bl   = (const float*)d_in[11];
  const float* lng  = (const float*)d_in[12];
  const float* lnb  = (const float*)d_in[13];
  const float* Wg1  = (const float*)d_in[14];
  const float* bg1  = (const float*)d_in[15];
  const float* Wg2  = (const float*)d_in[16];
  const float* bg2  = (const float*)d_in[17];
  const int*   ei   = (const int*)d_in[18];
  const int*   batch= (const int*)d_in[19];
  float* out = (float*)d_out;

  char* w = (char*)d_ws;
  auto alloc = [&](size_t bytes){ char* p = w; w += (bytes + 255) & ~(size_t)255; return p; };
  float* h    = (float*)alloc((size_t)N_NODES*128*4);
  unsigned short* xpb = (unsigned short*)alloc((size_t)N_NODES*128*2);
  float* asn  = (float*)alloc((size_t)N_NODES*4*4);
  float* adn  = (float*)alloc((size_t)N_NODES*4*4);
  float* crit = (float*)alloc((size_t)N_NODES*4);
  int*   cnt  = (int*)alloc((size_t)N_NODES*4);
  int*   incl = (int*)alloc((size_t)N_NODES*4);
  int*   part = (int*)alloc(256*4);
  int*   off  = (int*)alloc((size_t)(N_NODES+1)*4);
  int*   rank = (int*)alloc((size_t)N_EDGES*4);
  int2*  es   = (int2*)alloc((size_t)N_EDGES*8);
  float* gate = (float*)alloc((size_t)N_NODES*4);
  int*   start= (int*)alloc((size_t)(N_B+1)*4);
  unsigned short* WinT = (unsigned short*)alloc((size_t)128*128*2);
  unsigned short* WlT  = (unsigned short*)alloc((size_t)4*144*128*2);
  unsigned short* Wg1T = (unsigned short*)alloc((size_t)64*128*2);

  int nb_n = (N_NODES + 255)/256;   // 196
  int nb_w = (N_NODES + 3)/4;       // 12500 (one wave per node)
  int nb_g = (N_NODES + 63)/64;     // 782
  int nb_cs = 384 + nb_n;           // conv blocks + setup blocks
  int nb_4e = (200000 + 255)/256;   // 782

  k_convsetup<<<nb_cs,256,0,stream>>>(Win, Wl, a_src, a_dst, Wg1, batch,
                                      WinT, WlT, Wg1T, start, cnt);
  k_hist<<<nb_4e,256,0,stream>>>(ei, cnt, rank);
  k_mgemm<8,0><<<nb_g,256,0,stream>>>(x, WinT, b_in, h,
                                      nullptr, nullptr, nullptr, nullptr, nullptr, nullptr);
  k_scan1<<<nb_n,256,0,stream>>>(cnt, incl, part);
  k_scan23<<<nb_n,256,0,stream>>>(cnt, incl, part, off);
  k_fill<<<nb_4e,256,0,stream>>>(ea, We1, be1, We2, be2, ei, off, rank, es);
  for (int l = 0; l < 4; l++){
    k_mgemm<9,1><<<nb_g,256,0,stream>>>(h, WlT + (size_t)l*144*128, nullptr, nullptr,
                                        xpb, asn, adn, nullptr, nullptr, nullptr);
    if (l == 0)
      k_aggr<true><<<nb_w,256,0,stream>>>(xpb, asn, adn, off, es,
                                          bl + l*128, lng + l*128, lnb + l*128, crit, h);
    else
      k_aggr<false><<<nb_w,256,0,stream>>>(xpb, asn, adn, off, es,
                                           bl + l*128, lng + l*128, lnb + l*128, crit, h);
  }
  k_mgemm<4,2><<<nb_g,256,0,stream>>>(h, Wg1T, bg1, nullptr,
                                      nullptr, nullptr, nullptr, Wg2, bg2, gate);
  k_pool<<<N_B,256,0,stream>>>(h, gate, start, out);
}

// Round 11
// 428.529 us; speedup vs baseline: 1.1455x; 1.0269x over previous
//
#include <hip/hip_runtime.h>
#include <math.h>

#define N_NODES 50000
#define N_EDGES 800000
#define N_B     64

typedef __attribute__((ext_vector_type(8))) short v8s;
typedef __attribute__((ext_vector_type(4))) float v4f;
typedef __attribute__((ext_vector_type(2))) float v2f;

__device__ __forceinline__ float lrelu(float x){ return x > 0.f ? x : 0.2f*x; }
__device__ __forceinline__ unsigned short f2b(float f){   // fp32 -> bf16 RNE
  unsigned u = __float_as_uint(f);
  return (unsigned short)((u + 0x7fffu + ((u >> 16) & 1u)) >> 16);
}
__device__ __forceinline__ float blo(unsigned u){ return __uint_as_float(u << 16); }
__device__ __forceinline__ float bhi(unsigned u){ return __uint_as_float(u & 0xffff0000u); }

// ---------------- conv (weights->bf16^T, fused attn cols) + setup (cnt=0, bounds, out=0) ----------------
__global__ void k_convsetup(const float* __restrict__ Win, const float* __restrict__ Wl,
                            const float* __restrict__ a_src, const float* __restrict__ a_dst,
                            const float* __restrict__ Wg1, const int* __restrict__ batch,
                            unsigned short* __restrict__ WinT, unsigned short* __restrict__ WlT,
                            unsigned short* __restrict__ Wg1T, int* __restrict__ start,
                            int* __restrict__ cnt, float* __restrict__ out){
  if (blockIdx.x >= 384){                             // ---- setup part ----
    int i = (blockIdx.x - 384)*256 + threadIdx.x;
    if (i >= N_NODES) return;
    cnt[i] = 0;
    if (i < N_B*128) out[i] = 0.f;                    // k_pool accumulates into out
    int b = batch[i];
    int bp = (i == 0) ? -1 : batch[i-1];
    for (int j = bp+1; j <= b; j++) start[j] = i;
    if (i == N_NODES-1){
      for (int j = b+1; j <= N_B; j++) start[j] = N_NODES;
    }
    return;
  }
  int i = blockIdx.x*256 + threadIdx.x;
  if (i < 16384){
    int n = i >> 7, k = i & 127;
    WinT[n*128+k] = f2b(Win[k*128+n]);
    return;
  }
  i -= 16384;
  if (i < 65536){
    int l = i >> 14, n = (i >> 7) & 127, k = i & 127;
    WlT[l*144*128 + n*128 + k] = f2b(Wl[l*16384 + k*128 + n]);
    return;
  }
  i -= 65536;
  if (i < 4096){
    int l = i >> 10, k = (i >> 3) & 127, t = i & 7;
    int hh = t & 3, sd = t >> 2;
    const float* av = (sd ? a_dst : a_src) + l*128 + hh*32;
    const float* wr = Wl + l*16384 + k*128 + hh*32;
    float s = 0.f;
    #pragma unroll
    for (int c = 0; c < 32; c++) s = fmaf(wr[c], av[c], s);
    WlT[l*144*128 + (128 + sd*4 + hh)*128 + k] = f2b(s);
    return;
  }
  i -= 4096;
  if (i < 4096){
    int l = i >> 10, r = (i >> 7) & 7, k = i & 127;
    WlT[l*144*128 + (136+r)*128 + k] = 0;
    return;
  }
  i -= 4096;
  if (i < 8192){
    int n = i >> 7, k = i & 127;
    Wg1T[n*128+k] = f2b(Wg1[k*64+n]);
  }
}

// ---------------- degree histogram + per-edge rank: 8 edges/thread for atomic MLP ----------------
__global__ void k_hist(const int* __restrict__ ei, int* __restrict__ cnt, int* __restrict__ rank){
  int t = blockIdx.x*256 + threadIdx.x;
  if (t >= 100000) return;
  #pragma unroll
  for (int r = 0; r < 8; r++){
    int e = t + r*100000;
    int d = ei[N_EDGES + e];
    rank[e] = atomicAdd(&cnt[d], 1);
  }
}

// ---------------- scan1: per-block inclusive scan ----------------
__global__ void k_scan1(const int* __restrict__ cnt, int* __restrict__ incl, int* __restrict__ part){
  __shared__ int sh[256];
  int tid = threadIdx.x, i = blockIdx.x*256 + tid;
  int v = (i < N_NODES) ? cnt[i] : 0;
  sh[tid] = v; __syncthreads();
  for (int off = 1; off < 256; off <<= 1){
    int t = (tid >= off) ? sh[tid-off] : 0;
    __syncthreads();
    sh[tid] += t; __syncthreads();
  }
  if (i < N_NODES) incl[i] = sh[tid];
  if (tid == 255) part[blockIdx.x] = sh[255];
}
// ---------------- scan23: each block reduces part[0..blockIdx) then writes off ----------------
__global__ void k_scan23(const int* __restrict__ cnt, const int* __restrict__ incl,
                         const int* __restrict__ part, int* __restrict__ off){
  __shared__ int red[4];
  __shared__ int bsum;
  int tid = threadIdx.x, lane = tid & 63, wave = tid >> 6;
  int v = (tid < (int)blockIdx.x) ? part[tid] : 0;   // 196 blocks < 256 threads
  #pragma unroll
  for (int m = 1; m < 64; m <<= 1) v += __shfl_xor(v, m);
  if (lane == 0) red[wave] = v;
  __syncthreads();
  if (tid == 0) bsum = red[0]+red[1]+red[2]+red[3];
  __syncthreads();
  int i = blockIdx.x*256 + tid;
  if (i >= N_NODES) return;
  int e = incl[i] - cnt[i] + bsum;
  off[i] = e;
  if (i == N_NODES-1) off[N_NODES] = e + cnt[i];
}

// ---------------- CSR fill + edge MLP scalar (atomic-free, single 8B scatter) ----------------
__global__ void k_fill(const float* __restrict__ ea, const float* __restrict__ We1,
                       const float* __restrict__ be1, const float* __restrict__ We2,
                       const float* __restrict__ be2, const int* __restrict__ ei,
                       const int* __restrict__ off, const int* __restrict__ rank,
                       int2* __restrict__ es){
  __shared__ float w0[16], w1[16], bb[16], w2s[16];
  __shared__ float b2s;
  int tid = threadIdx.x;
  if (tid < 16){
    w0[tid] = We1[tid]; w1[tid] = We1[16+tid]; bb[tid] = be1[tid];
    w2s[tid] = 0.25f*(We2[tid*4]+We2[tid*4+1]+We2[tid*4+2]+We2[tid*4+3]);
  }
  if (tid == 0) b2s = 0.25f*(be2[0]+be2[1]+be2[2]+be2[3]);
  __syncthreads();
  int t = blockIdx.x*256 + tid;
  if (t >= 100000) return;
  #pragma unroll
  for (int r = 0; r < 8; r++){
    int e = t + r*100000;
    float a0 = ea[2*e], a1 = ea[2*e+1];
    float s = b2s;
    #pragma unroll
    for (int j = 0; j < 16; j++){
      float v = fmaf(a0, w0[j], fmaf(a1, w1[j], bb[j]));
      v = v > 0.f ? v : 0.f;
      s = fmaf(v, w2s[j], s);
    }
    int d = ei[N_EDGES + e];
    int p = off[d] + rank[e];
    es[p] = make_int2(ei[e], __float_as_int(s));
  }
}

// ---------------- MFMA GEMM (A always fp32 h/x, converted during staging) ----------------
template<int NT, int MODE>
__global__ __launch_bounds__(256) void k_mgemm(
    const float* __restrict__ A, const unsigned short* __restrict__ Bt,
    const float* __restrict__ bias,
    float* __restrict__ h,
    unsigned short* __restrict__ xpb, float* __restrict__ asn, float* __restrict__ adn,
    const float* __restrict__ Wg2, const float* __restrict__ bg2, float* __restrict__ gate)
{
  __shared__ __attribute__((aligned(16))) unsigned short Bs[NT*16][136];
  __shared__ __attribute__((aligned(16))) unsigned short As[4][16][136];
  int tid = threadIdx.x, wave = tid >> 6, lane = tid & 63;
  int l15 = lane & 15, quad = lane >> 4;
  int rbase = blockIdx.x * 64;
  for (int id = tid; id < NT*16*16; id += 256){
    int r = id >> 4, ch = id & 15;
    *(v8s*)&Bs[r][ch*8] = *(const v8s*)(Bt + r*128 + ch*8);
  }
  for (int id = tid; id < 64*16; id += 256){
    int r = id >> 4, ch = id & 15;
    int gr = rbase + r;
    v8s v = {0,0,0,0,0,0,0,0};
    if (gr < N_NODES){
      const float* Af = A + (size_t)gr*128 + ch*8;
      float4 va = *(const float4*)Af;
      float4 vb = *(const float4*)(Af + 4);
      v[0]=(short)f2b(va.x); v[1]=(short)f2b(va.y); v[2]=(short)f2b(va.z); v[3]=(short)f2b(va.w);
      v[4]=(short)f2b(vb.x); v[5]=(short)f2b(vb.y); v[6]=(short)f2b(vb.z); v[7]=(short)f2b(vb.w);
    }
    *(v8s*)&As[r >> 4][r & 15][ch*8] = v;
  }
  __syncthreads();
  v4f acc[NT];
  #pragma unroll
  for (int t = 0; t < NT; t++) acc[t] = (v4f){0.f,0.f,0.f,0.f};
  #pragma unroll
  for (int kb = 0; kb < 4; kb++){
    v8s a = *(v8s*)&As[wave][l15][kb*32 + quad*8];
    #pragma unroll
    for (int ct = 0; ct < NT; ct++){
      v8s b = *(v8s*)&Bs[ct*16 + l15][kb*32 + quad*8];
      acc[ct] = __builtin_amdgcn_mfma_f32_16x16x32_bf16(a, b, acc[ct], 0, 0, 0);
    }
  }
  int row0 = rbase + wave*16 + quad*4;
  if (MODE == 0){
    #pragma unroll
    for (int ct = 0; ct < 8; ct++){
      float bcol = bias[ct*16 + l15];
      #pragma unroll
      for (int r = 0; r < 4; r++){
        int gr = row0 + r;
        if (gr < N_NODES) h[(size_t)gr*128 + ct*16 + l15] = acc[ct][r] + bcol;
      }
    }
  } else if (MODE == 1){
    #pragma unroll
    for (int ct = 0; ct < 8; ct++){
      #pragma unroll
      for (int r = 0; r < 4; r++){
        int gr = row0 + r;
        if (gr < N_NODES) xpb[(size_t)gr*128 + ct*16 + l15] = f2b(acc[ct][r]);
      }
    }
    #pragma unroll
    for (int r = 0; r < 4; r++){
      int gr = row0 + r;
      if (gr < N_NODES){
        float v = acc[NT-1][r];
        if (l15 < 4) asn[gr*4 + l15] = v;
        else if (l15 < 8) adn[gr*4 + (l15-4)] = v;
      }
    }
  } else {
    float part[4] = {0.f,0.f,0.f,0.f};
    #pragma unroll
    for (int ct = 0; ct < NT; ct++){
      float b1 = bias[ct*16 + l15];
      float w2 = Wg2[ct*16 + l15];
      #pragma unroll
      for (int r = 0; r < 4; r++) part[r] = fmaf(tanhf(acc[ct][r] + b1), w2, part[r]);
    }
    #pragma unroll
    for (int m = 1; m < 16; m <<= 1){
      #pragma unroll
      for (int r = 0; r < 4; r++) part[r] += __shfl_xor(part[r], m);
    }
    if (l15 == 0){
      float b2 = bg2[0];
      #pragma unroll
      for (int r = 0; r < 4; r++){
        int gr = row0 + r;
        if (gr < N_NODES) gate[gr] = part[r] + b2;
      }
    }
  }
}

// ---------------- per-node GAT softmax + aggregate + bias + LN + crit + residual ----------------
// v9: v8 (e_self shift, in-register denom) + 12-deep gather pipeline.
// TLP hides gather latency: keep VGPR well under 44, LDS 4KB (R8 lesson).
template<bool CRIT>
__global__ __launch_bounds__(256) void k_aggr(
    const unsigned short* __restrict__ xpb, const float* __restrict__ asn,
    const float* __restrict__ adn, const int* __restrict__ off,
    const int2* __restrict__ es,
    const float* __restrict__ bl, const float* __restrict__ lng,
    const float* __restrict__ lnb, float* __restrict__ crit,
    float* __restrict__ h)
{
  __shared__ float lp[4][256];
  int wave = threadIdx.x >> 6, lane = threadIdx.x & 63;
  int n = blockIdx.x*4 + wave;
  if (n >= N_NODES) return;
  int base = off[n], deg = off[n+1] - base;
  float4 ad4 = *(const float4*)(adn + n*4);
  float4 asf = *(const float4*)(asn + n*4);
  float ex = lrelu(asf.x+ad4.x), ey = lrelu(asf.y+ad4.y);
  float ez = lrelu(asf.z+ad4.z), ew = lrelu(asf.w+ad4.w);
  const unsigned* xw = (const unsigned*)xpb;
  float* myp = &lp[wave][0];
  int hh = lane >> 4;
  float cr, dsum = 0.f;
  v2f acc;
  unsigned us = (xw + ((size_t)(unsigned)n << 6))[lane];
  acc.x = blo(us); acc.y = bhi(us);                   // self numerator == exp(0) == 1

  if (deg <= 64){
    int sreg = 0;
    float cw = 0.f;
    float p0 = 0.f, p1 = 0.f, p2 = 0.f, p3 = 0.f;
    if (lane < deg){
      int2 er = es[base + lane];
      sreg = er.x;
      float4 a = *(const float4*)(asn + sreg*4);
      p0 = __expf(lrelu(a.x+ad4.x) - ex);
      p1 = __expf(lrelu(a.y+ad4.y) - ey);
      p2 = __expf(lrelu(a.z+ad4.z) - ez);
      p3 = __expf(lrelu(a.w+ad4.w) - ew);
      if (CRIT) cw = __int_as_float(er.y);
    }
    if (CRIT){
      #pragma unroll
      for (int m = 1; m < 64; m <<= 1) cw += __shfl_xor(cw, m);
      if (lane == 0) crit[n] = cw;
      cr = cw;
    } else cr = crit[n];
    *(float4*)(&myp[4*lane]) = make_float4(p0,p1,p2,p3);
    __threadfence_block();
    int degR = ((deg + 11) / 12) * 12;
    for (int c = 0; c < degR; c += 12){
      unsigned u[12];
      #pragma unroll
      for (int k = 0; k < 12; k++){
        int s0 = __builtin_amdgcn_readlane(sreg, c + k);
        u[k] = (xw + ((size_t)(unsigned)s0 << 6))[lane];     // SGPR base + lane*4
      }
      #pragma unroll
      for (int k = 0; k < 12; k++){
        float q = myp[4*(c+k) + hh];
        dsum += q;                                           // full denom, no reduce
        v2f v = {blo(u[k]), bhi(u[k])};
        acc += q * v;
      }
    }
    __threadfence_block();
  } else {
    // ---- general path (rare): tile loop; crit pass only in layer 0 ----
    if (CRIT){
      float cw = 0.f;
      for (int j = lane; j < deg; j += 64) cw += __int_as_float(es[base + j].y);
      #pragma unroll
      for (int m = 1; m < 64; m <<= 1) cw += __shfl_xor(cw, m);
      if (lane == 0) crit[n] = cw;
      cr = cw;
    } else cr = crit[n];
    for (int j0 = 0; j0 < deg; j0 += 64){
      int clen = deg - j0; if (clen > 64) clen = 64;
      int sreg = 0;
      float p0 = 0.f, p1 = 0.f, p2 = 0.f, p3 = 0.f;
      if (lane < clen){
        sreg = es[base + j0 + lane].x;
        float4 a = *(const float4*)(asn + sreg*4);
        p0 = __expf(lrelu(a.x+ad4.x) - ex);
        p1 = __expf(lrelu(a.y+ad4.y) - ey);
        p2 = __expf(lrelu(a.z+ad4.z) - ez);
        p3 = __expf(lrelu(a.w+ad4.w) - ew);
      }
      *(float4*)(&myp[4*lane]) = make_float4(p0,p1,p2,p3);
      __threadfence_block();
      int clenR = (clen + 7) & ~7;
      for (int c = 0; c < clenR; c += 8){
        unsigned u[8];
        #pragma unroll
        for (int k = 0; k < 8; k++){
          int s0 = __builtin_amdgcn_readlane(sreg, c + k);
          u[k] = (xw + ((size_t)(unsigned)s0 << 6))[lane];
        }
        #pragma unroll
        for (int k = 0; k < 8; k++){
          float q = myp[4*(c+k) + hh];
          dsum += q;
          v2f v = {blo(u[k]), bhi(u[k])};
          acc += q * v;
        }
      }
      __threadfence_block();
    }
  }
  float rden = 1.f / (dsum + 1.f + 1e-16f);            // +1 = self term
  int c0 = 2*lane;
  float2 blv = *(const float2*)(bl + c0);
  float o0 = acc.x*rden + blv.x;
  float o1 = acc.y*rden + blv.y;
  float su = o0 + o1, sq = o0*o0 + o1*o1;
  #pragma unroll
  for (int m = 1; m < 64; m <<= 1){ su += __shfl_xor(su, m); sq += __shfl_xor(sq, m); }
  float mu  = su * (1.f/128.f);
  float var = sq * (1.f/128.f) - mu*mu; var = var > 0.f ? var : 0.f;
  float inv = rsqrtf(var + 1e-5f);
  float2 rv  = *(const float2*)(h + (size_t)n*128 + c0);
  float2 gv  = *(const float2*)(lng + c0);
  float2 bv2 = *(const float2*)(lnb + c0);
  o0 = (o0-mu)*inv*gv.x + bv2.x + cr + rv.x;
  o1 = (o1-mu)*inv*gv.y + bv2.y + cr + rv.y;
  *(float2*)(&h[(size_t)n*128 + c0]) = make_float2(o0, o1);
}

// ---------------- pooling: 4 blocks per graph; A/B recomputed per block (no gate write),
// phase-C quarter partials accumulated into zero-initialized out via atomicAdd ----------------
__global__ __launch_bounds__(256) void k_pool(
    const float* __restrict__ h, const float* __restrict__ gate,
    const int* __restrict__ start, float* __restrict__ out)
{
  __shared__ float red[4];
  __shared__ float sbc;
  __shared__ float4 accs[8][32];
  int b = blockIdx.x >> 2, quarter = blockIdx.x & 3;
  int s0 = start[b], s1 = start[b+1];
  int tid = threadIdx.x, lane = tid & 63, wave = tid >> 6;
  // phase A: segment max (read-only)
  float m = -3.0e38f;
  for (int i = s0 + tid; i < s1; i += 256) m = fmaxf(m, gate[i]);
  #pragma unroll
  for (int k = 1; k < 64; k <<= 1) m = fmaxf(m, __shfl_xor(m, k));
  if (lane == 0) red[wave] = m;
  __syncthreads();
  if (tid == 0) sbc = fmaxf(fmaxf(red[0],red[1]), fmaxf(red[2],red[3]));
  __syncthreads();
  float gm = sbc;
  __syncthreads();
  // phase B: segment sum of exp (read-only, recomputed identically in all 4 blocks)
  float s = 0.f;
  for (int i = s0 + tid; i < s1; i += 256) s += __expf(gate[i] - gm);
  #pragma unroll
  for (int k = 1; k < 64; k <<= 1) s += __shfl_xor(s, k);
  if (lane == 0) red[wave] = s;
  __syncthreads();
  if (tid == 0) sbc = red[0]+red[1]+red[2]+red[3];
  __syncthreads();
  float inv = 1.f / (sbc + 1e-16f);
  // phase C: this quarter's nodes (stride 32 = 4 quarters x 8 groups)
  int c4 = (tid & 31) * 4;
  int g  = tid >> 5;
  float4 acc = make_float4(0.f,0.f,0.f,0.f);
  for (int i = s0 + quarter*8 + g; i < s1; i += 32){
    float p = __expf(gate[i] - gm);
    float4 hv = *(const float4*)(h + (size_t)i*128 + c4);
    acc.x = fmaf(p,hv.x,acc.x); acc.y = fmaf(p,hv.y,acc.y);
    acc.z = fmaf(p,hv.z,acc.z); acc.w = fmaf(p,hv.w,acc.w);
  }
  accs[g][tid & 31] = acc;
  __syncthreads();
  if (g == 0){
    float4 t = acc;
    #pragma unroll
    for (int k = 1; k < 8; k++){
      float4 o = accs[k][tid & 31];
      t.x += o.x; t.y += o.y; t.z += o.z; t.w += o.w;
    }
    atomicAdd(out + b*128 + c4 + 0, t.x*inv);
    atomicAdd(out + b*128 + c4 + 1, t.y*inv);
    atomicAdd(out + b*128 + c4 + 2, t.z*inv);
    atomicAdd(out + b*128 + c4 + 3, t.w*inv);
  }
}

extern "C" void kernel_launch(void* const* d_in, const int* in_sizes, int n_in,
                              void* d_out, int out_size, void* d_ws, size_t ws_size,
                              hipStream_t stream){
  (void)in_sizes; (void)n_in; (void)out_size; (void)ws_size;
  const float* x    = (const float*)d_in[0];
  const float* ea   = (const float*)d_in[1];
  const float* Win  = (const float*)d_in[2];
  const float* b_in = (const float*)d_in[3];
  const float* We1  = (const float*)d_in[4];
  const float* be1  = (const float*)d_in[5];
  const float* We2  = (const float*)d_in[6];
  const float* be2  = (const float*)d_in[7];
  const float* Wl   = (const float*)d_in[8];
  const float* a_src= (const float*)d_in[9];
  const float* a_dst= (const float*)d_in[10];
  const float* bl   = (const float*)d_in[11];
  const float* lng  = (const float*)d_in[12];
  const float* lnb  = (const float*)d_in[13];
  const float* Wg1  = (const float*)d_in[14];
  const float* bg1  = (const float*)d_in[15];
  const float* Wg2  = (const float*)d_in[16];
  const float* bg2  = (const float*)d_in[17];
  const int*   ei   = (const int*)d_in[18];
  const int*   batch= (const int*)d_in[19];
  float* out = (float*)d_out;

  char* w = (char*)d_ws;
  auto alloc = [&](size_t bytes){ char* p = w; w += (bytes + 255) & ~(size_t)255; return p; };
  float* h    = (float*)alloc((size_t)N_NODES*128*4);
  unsigned short* xpb = (unsigned short*)alloc((size_t)N_NODES*128*2);
  float* asn  = (float*)alloc((size_t)N_NODES*4*4);
  float* adn  = (float*)alloc((size_t)N_NODES*4*4);
  float* crit = (float*)alloc((size_t)N_NODES*4);
  int*   cnt  = (int*)alloc((size_t)N_NODES*4);
  int*   incl = (int*)alloc((size_t)N_NODES*4);
  int*   part = (int*)alloc(256*4);
  int*   off  = (int*)alloc((size_t)(N_NODES+1)*4);
  int*   rank = (int*)alloc((size_t)N_EDGES*4);
  int2*  es   = (int2*)alloc((size_t)N_EDGES*8);
  float* gate = (float*)alloc((size_t)N_NODES*4);
  int*   start= (int*)alloc((size_t)(N_B+1)*4);
  unsigned short* WinT = (unsigned short*)alloc((size_t)128*128*2);
  unsigned short* WlT  = (unsigned short*)alloc((size_t)4*144*128*2);
  unsigned short* Wg1T = (unsigned short*)alloc((size_t)64*128*2);

  int nb_n = (N_NODES + 255)/256;   // 196
  int nb_w = (N_NODES + 3)/4;       // 12500 (one wave per node)
  int nb_g = (N_NODES + 63)/64;     // 782
  int nb_cs = 384 + nb_n;           // conv blocks + setup blocks
  int nb_8e = (100000 + 255)/256;   // 391

  k_convsetup<<<nb_cs,256,0,stream>>>(Win, Wl, a_src, a_dst, Wg1, batch,
                                      WinT, WlT, Wg1T, start, cnt, out);
  k_hist<<<nb_8e,256,0,stream>>>(ei, cnt, rank);
  k_mgemm<8,0><<<nb_g,256,0,stream>>>(x, WinT, b_in, h,
                                      nullptr, nullptr, nullptr, nullptr, nullptr, nullptr);
  k_scan1<<<nb_n,256,0,stream>>>(cnt, incl, part);
  k_scan23<<<nb_n,256,0,stream>>>(cnt, incl, part, off);
  k_fill<<<nb_8e,256,0,stream>>>(ea, We1, be1, We2, be2, ei, off, rank, es);
  for (int l = 0; l < 4; l++){
    k_mgemm<9,1><<<nb_g,256,0,stream>>>(h, WlT + (size_t)l*144*128, nullptr, nullptr,
                                        xpb, asn, adn, nullptr, nullptr, nullptr);
    if (l == 0)
      k_aggr<true><<<nb_w,256,0,stream>>>(xpb, asn, adn, off, es,
                                          bl + l*128, lng + l*128, lnb + l*128, crit, h);
    else
      k_aggr<false><<<nb_w,256,0,stream>>>(xpb, asn, adn, off, es,
                                           bl + l*128, lng + l*128, lnb + l*128, crit, h);
  }
  k_mgemm<4,2><<<nb_g,256,0,stream>>>(h, Wg1T, bg1, nullptr,
                                      nullptr, nullptr, nullptr, Wg2, bg2, gate);
  k_pool<<<N_B*4,256,0,stream>>>(h, gate, start, out);
}